// Round 6
// baseline (619.039 us; speedup 1.0000x reference)
//
#include <hip/hip_runtime.h>
#include <hip/hip_bf16.h>

// CausalSelfAttention: B=8 T=1024 C=2048 NH=16 HD=128. FP32 I/O, bf16 MFMA.
// R11: 8-phase GEMMs rebalanced to per-phase-consumed ds_reads (m201 pattern):
// quadrant order Q00,Q01,Q11,Q10 -> reads 12/4/8/0 (was 16/8/0/0). B-stages
// moved +1/+2 -> +2/+3 (B-reads end +1; consuming MFMA's lgkmcnt completes
// them before the barrier preceding the overwriting stage). vmcnt(6) and
// prologue unchanged (in-flight groups at +3 wait: 2+4 = 6). attn unchanged.
// ws: Wat^T 24M | Wpt^T 8M | Q 32M (y overwrites Q after attn) | [xb 32M].
// d_out: K bf16 | V bf16 until proj GEMM overwrites with fp32 result.

typedef unsigned short u16;
typedef __bf16 bf16x8 __attribute__((ext_vector_type(8)));
typedef float f32x4 __attribute__((ext_vector_type(4)));

#define B_ 8
#define T_ 1024
#define C_ 2048
#define NH 16
#define HD 128
#define BH (B_*NH)

__device__ __forceinline__ u16 f2b(float f){
  __bf16 h = (__bf16)f; return __builtin_bit_cast(u16, h);   // RNE
}
__device__ __forceinline__ unsigned pk2(float x, float y){
  return (unsigned)f2b(x) | ((unsigned)f2b(y) << 16);
}
__device__ __forceinline__ bf16x8 ldfrag(const u16* p){
  uint4 u = *(const uint4*)p; return __builtin_bit_cast(bf16x8, u);
}
__device__ __forceinline__ void glds16(const u16* g, const u16* l){
  __builtin_amdgcn_global_load_lds(
      (const __attribute__((address_space(1))) void*)g,
      (__attribute__((address_space(3))) void*)l, 16, 0, 0);
}
__device__ __forceinline__ void sbar(){
  __builtin_amdgcn_sched_barrier(0);
  __builtin_amdgcn_s_barrier();
  __builtin_amdgcn_sched_barrier(0);
}

// ---------------- fp32 -> bf16 pack, n4 = n/4 ------------------------------
__global__ __launch_bounds__(256) void cvt_bf16(
    const float4* __restrict__ in, ushort4* __restrict__ outp, int n4)
{
  int i = blockIdx.x*256 + threadIdx.x;
  const int stride = gridDim.x*256;
  for (; i < n4; i += stride){
    float4 f = in[i];
    ushort4 o; o.x = f2b(f.x); o.y = f2b(f.y); o.z = f2b(f.z); o.w = f2b(f.w);
    outp[i] = o;
  }
}

// ---------------- W fp32 [R][C] -> bf16 W^T [C][R], 64x64 tiles --------------
__global__ __launch_bounds__(256) void transpose_cvt(
    const float* __restrict__ in, u16* __restrict__ outp, int R, int C)
{
  __shared__ u16 tile[64][65];
  const int t = threadIdx.x;
  const int r0 = blockIdx.y * 64, c0 = blockIdx.x * 64;
#pragma unroll
  for (int ii = 0; ii < 16; ++ii){
    int idx = t + ii*256; int r = idx >> 6, c = idx & 63;
    tile[r][c] = f2b(in[(size_t)(r0 + r)*C + c0 + c]);
  }
  __syncthreads();
#pragma unroll
  for (int ii = 0; ii < 16; ++ii){
    int idx = t + ii*256; int r = idx >> 6, c = idx & 63;
    outp[(size_t)(c0 + r)*R + r0 + c] = tile[c][r];
  }
}

// ---------------- QKV epilogue for 128-tile fallback path -------------------
__device__ __forceinline__ void qkv_epilogue(
    const f32x4 acc[4][4], const float* bias, int bx, int by,
    int wm, int wn, int lq, int ln,
    u16* qb, u16* kb, u16* vb)
{
  const int tensor = bx >> 4, h = bx & 15, b = by >> 3, t0 = (by & 7)*128;
  u16* tb = tensor==0 ? qb : (tensor==1 ? kb : vb);
  u16* op = tb + ((size_t)(b*NH + h)*T_ + t0)*HD;
#pragma unroll
  for (int j=0;j<4;j++){
    const float bv = bias[bx*128 + wn*64 + j*16 + ln];
    const int n = wn*64 + j*16 + ln;
#pragma unroll
    for (int i=0;i<4;i++){
      const int m0 = wm*64 + i*16 + lq*4;      // C/D: row = quad*4 + reg
#pragma unroll
      for (int r=0;r<4;r++)
        op[(size_t)(m0 + r)*HD + n] = f2b(acc[i][j][r] + bv);
    }
  }
}

// ---------------- QKV GEMM, 256x256 8-phase, R11 rebalanced -----------------
__global__ __launch_bounds__(512,2) void gemm_qkv_8p(
    const u16* __restrict__ Xb, const u16* __restrict__ Wt,
    const float* __restrict__ bias,
    u16* __restrict__ qb, u16* __restrict__ kb, u16* __restrict__ vb)
{
  __shared__ u16 lds[2][2][256*64];            // [buf][A/B][row][k] 128 KiB
  const int t = threadIdx.x;                   // 0..511
  const int lane = t & 63, wid = t >> 6;       // 8 waves: 2M x 4N
  const int lq = lane >> 4, ln = lane & 15;
  const int wm = wid >> 2, wn = wid & 3;

  // XCD-aware swizzle (768 blocks, 768%8==0 -> simple form is bijective)
  const int bid0 = blockIdx.x;
  const int bid = (bid0 & 7)*96 + (bid0 >> 3);
  const int bx = bid % 24, by = bid / 24;      // bx: N/256, by: M/256

  const int rl  = (wid << 4) + (lane >> 3);    // q=0 local row (0..127)
  const int sw0 = (lane & 7) ^ (rl & 7);
  const u16* Ag = Xb + ((size_t)(by*256) + rl)*2048;
  const u16* Bg = Wt + ((size_t)(bx*256) + rl)*2048;
  const size_t q0off = (size_t)sw0*8;
  const size_t q1off = (size_t)8*2048 + (size_t)sw0*8;   // (rl+8)&7 == rl&7

#define STAGE(buf_, op_, h_, T_) do { \
    const u16* s_ = (op_ ? Bg : Ag) + (size_t)(h_)*(128*2048) + (size_t)(T_)*64; \
    const u16* d_ = &lds[buf_][op_][(((h_)*128) + (wid<<4))*64]; \
    glds16(s_ + q0off, d_); \
    glds16(s_ + q1off, d_ + 8*64); \
  } while(0)

  const int swr0 = (0*4 + lq) ^ (ln & 7);
  const int swr1 = (1*4 + lq) ^ (ln & 7);

  const f32x4 fz = {0.f,0.f,0.f,0.f};
  f32x4 acc[8][4];
#pragma unroll
  for (int f=0;f<8;f++)
#pragma unroll
    for (int g=0;g<4;g++) acc[f][g] = fz;

  // prologue: tile0 fully + tile1's Bhi,Blo,Ahi (Alo(1) comes at (0,+0))
  STAGE(0,0,0,0); STAGE(0,0,1,0); STAGE(0,1,0,0); STAGE(0,1,1,0);
  STAGE(1,1,0,1); STAGE(1,1,1,1); STAGE(1,0,0,1);
  asm volatile("s_waitcnt vmcnt(6)" ::: "memory");   // tile0 landed
  sbar();

  for (int T = 0; T < 32; ++T){
    const int b = T & 1;
    const u16* As = lds[b][0];
    const u16* Bs = lds[b][1];
    bf16x8 a0[4][2], a4[4][2], b01[2][2], b23[2][2];

    // ---- phase +0: read A0 (8) + B0 (4); stage A-h1(T+1)->b^1; MFMA f0-3 g0-1
#pragma unroll
    for (int f=0;f<4;f++){
      a0[f][0] = ldfrag(&As[(wm*128 + f*16 + ln)*64 + swr0*8]);
      a0[f][1] = ldfrag(&As[(wm*128 + f*16 + ln)*64 + swr1*8]);
    }
#pragma unroll
    for (int g=0;g<2;g++){
      b01[g][0] = ldfrag(&Bs[(wn*64 + g*16 + ln)*64 + swr0*8]);
      b01[g][1] = ldfrag(&Bs[(wn*64 + g*16 + ln)*64 + swr1*8]);
    }
    if (T+1 < 32) STAGE(b^1, 0, 1, T+1);
    sbar();
    __builtin_amdgcn_s_setprio(1);
#pragma unroll
    for (int f=0;f<4;f++)
#pragma unroll
      for (int g=0;g<2;g++){
        acc[f][g] = __builtin_amdgcn_mfma_f32_16x16x32_bf16(a0[f][0], b01[g][0], acc[f][g], 0,0,0);
        acc[f][g] = __builtin_amdgcn_mfma_f32_16x16x32_bf16(a0[f][1], b01[g][1], acc[f][g], 0,0,0);
      }
    __builtin_amdgcn_s_setprio(0);
    sbar();

    // ---- phase +1: read B1 (4); no stage; MFMA f0-3 g2-3
#pragma unroll
    for (int g=0;g<2;g++){
      b23[g][0] = ldfrag(&Bs[(wn*64 + (g+2)*16 + ln)*64 + swr0*8]);
      b23[g][1] = ldfrag(&Bs[(wn*64 + (g+2)*16 + ln)*64 + swr1*8]);
    }
    sbar();
    __builtin_amdgcn_s_setprio(1);
#pragma unroll
    for (int f=0;f<4;f++)
#pragma unroll
      for (int g=0;g<2;g++){
        acc[f][g+2] = __builtin_amdgcn_mfma_f32_16x16x32_bf16(a0[f][0], b23[g][0], acc[f][g+2], 0,0,0);
        acc[f][g+2] = __builtin_amdgcn_mfma_f32_16x16x32_bf16(a0[f][1], b23[g][1], acc[f][g+2], 0,0,0);
      }
    __builtin_amdgcn_s_setprio(0);
    sbar();

    // ---- phase +2: read A1 (8); stage B-h0(T+2)->b; MFMA f4-7 g2-3
#pragma unroll
    for (int f=0;f<4;f++){
      a4[f][0] = ldfrag(&As[(wm*128 + (f+4)*16 + ln)*64 + swr0*8]);
      a4[f][1] = ldfrag(&As[(wm*128 + (f+4)*16 + ln)*64 + swr1*8]);
    }
    if (T+2 < 32) STAGE(b, 1, 0, T+2);
    sbar();
    __builtin_amdgcn_s_setprio(1);
#pragma unroll
    for (int f=0;f<4;f++)
#pragma unroll
      for (int g=0;g<2;g++){
        acc[f+4][g+2] = __builtin_amdgcn_mfma_f32_16x16x32_bf16(a4[f][0], b23[g][0], acc[f+4][g+2], 0,0,0);
        acc[f+4][g+2] = __builtin_amdgcn_mfma_f32_16x16x32_bf16(a4[f][1], b23[g][1], acc[f+4][g+2], 0,0,0);
      }
    __builtin_amdgcn_s_setprio(0);
    sbar();

    // ---- phase +3: no reads; stage B-h1(T+2)->b, A-h0(T+2)->b; counted vmcnt;
    //      MFMA f4-7 g0-1 (b01 register-held since +0)
    if (T+2 < 32){ STAGE(b, 1, 1, T+2); STAGE(b, 0, 0, T+2); }
    if (T >= 30) asm volatile("s_waitcnt vmcnt(0)" ::: "memory");
    else         asm volatile("s_waitcnt vmcnt(6)" ::: "memory");
    sbar();
    __builtin_amdgcn_s_setprio(1);
#pragma unroll
    for (int f=0;f<4;f++)
#pragma unroll
      for (int g=0;g<2;g++){
        acc[f+4][g] = __builtin_amdgcn_mfma_f32_16x16x32_bf16(a4[f][0], b01[g][0], acc[f+4][g], 0,0,0);
        acc[f+4][g] = __builtin_amdgcn_mfma_f32_16x16x32_bf16(a4[f][1], b01[g][1], acc[f+4][g], 0,0,0);
      }
    __builtin_amdgcn_s_setprio(0);
    sbar();
  }
#undef STAGE

  // epilogue: scatter to Q/K/V [BH][T][HD]
  const int tensor = bx >> 3;
  u16* tb = tensor==0 ? qb : (tensor==1 ? kb : vb);
  const int m_base = by*256 + wm*128;
#pragma unroll
  for (int g=0; g<4; ++g){
    const int ncol = (bx & 7)*256 + wn*64 + g*16 + ln;   // 0..2047 in tensor
    const float bv = bias[tensor*2048 + ncol];
    const int h = ncol >> 7, d = ncol & 127;
#pragma unroll
    for (int f=0; f<8; ++f){
      const int m0 = m_base + f*16 + lq*4;
      const int bb = m0 >> 10, tt = m0 & 1023;           // rows m0..m0+3 same b
      u16* op = tb + ((size_t)(bb*NH + h)*T_ + tt)*HD + d;
#pragma unroll
      for (int r=0;r<4;++r)
        op[(size_t)r*HD] = f2b(acc[f][g][r] + bv);
    }
  }
}

// ---------------- proj GEMM, 256x256 8-phase, R11 rebalanced ----------------
__global__ __launch_bounds__(512,2) void gemm_proj_8p(
    const u16* __restrict__ Y, const u16* __restrict__ Wt,
    const float* __restrict__ bias, float* __restrict__ outp)
{
  __shared__ u16 lds[2][2][256*64];            // [buf][A/B][row][k] 128 KiB
  const int t = threadIdx.x;
  const int lane = t & 63, wid = t >> 6;
  const int lq = lane >> 4, ln = lane & 15;
  const int wm = wid >> 2, wn = wid & 3;

  // 256 blocks, 256%8==0 -> bijective XCD swizzle
  const int bid0 = blockIdx.x;
  const int bid = (bid0 & 7)*32 + (bid0 >> 3);
  const int bx = bid & 7, by = bid >> 3;       // bx: N/256 (8), by: M/256 (32)

  const int rl  = (wid << 4) + (lane >> 3);
  const int sw0 = (lane & 7) ^ (rl & 7);
  const u16* Bg = Wt + ((size_t)(bx*256) + rl)*2048;
  const size_t bq0 = (size_t)sw0*8;
  const size_t arow0 = ((size_t)(by >> 2)*16)*1024 + (size_t)(by & 3)*256 + rl;

#define STAGEP(buf_, op_, h_, Tt_) do { \
    const u16* d_ = &lds[buf_][op_][(((h_)*128) + (wid<<4))*64]; \
    if (op_){ \
      const u16* s_ = Bg + (size_t)(h_)*(128*2048) + (size_t)(Tt_)*64; \
      glds16(s_ + bq0, d_); \
      glds16(s_ + (size_t)8*2048 + bq0, d_ + 8*64); \
    } else { \
      const u16* s_ = Y + (arow0 + (size_t)((Tt_) >> 1)*1024 + (size_t)(h_)*128)*128 \
                        + ((Tt_) & 1)*64 + sw0*8; \
      glds16(s_, d_); \
      glds16(s_ + 8*128, d_ + 8*64); \
    } \
  } while(0)

  const int swr0 = (0*4 + lq) ^ (ln & 7);
  const int swr1 = (1*4 + lq) ^ (ln & 7);

  const f32x4 fz = {0.f,0.f,0.f,0.f};
  f32x4 acc[8][4];
#pragma unroll
  for (int f=0;f<8;f++)
#pragma unroll
    for (int g=0;g<4;g++) acc[f][g] = fz;

  STAGEP(0,0,0,0); STAGEP(0,0,1,0); STAGEP(0,1,0,0); STAGEP(0,1,1,0);
  STAGEP(1,1,0,1); STAGEP(1,1,1,1); STAGEP(1,0,0,1);
  asm volatile("s_waitcnt vmcnt(6)" ::: "memory");
  sbar();

  for (int T = 0; T < 32; ++T){
    const int b = T & 1;
    const u16* As = lds[b][0];
    const u16* Bs = lds[b][1];
    bf16x8 a0[4][2], a4[4][2], b01[2][2], b23[2][2];

    // ---- phase +0
#pragma unroll
    for (int f=0;f<4;f++){
      a0[f][0] = ldfrag(&As[(wm*128 + f*16 + ln)*64 + swr0*8]);
      a0[f][1] = ldfrag(&As[(wm*128 + f*16 + ln)*64 + swr1*8]);
    }
#pragma unroll
    for (int g=0;g<2;g++){
      b01[g][0] = ldfrag(&Bs[(wn*64 + g*16 + ln)*64 + swr0*8]);
      b01[g][1] = ldfrag(&Bs[(wn*64 + g*16 + ln)*64 + swr1*8]);
    }
    if (T+1 < 32) STAGEP(b^1, 0, 1, T+1);
    sbar();
    __builtin_amdgcn_s_setprio(1);
#pragma unroll
    for (int f=0;f<4;f++)
#pragma unroll
      for (int g=0;g<2;g++){
        acc[f][g] = __builtin_amdgcn_mfma_f32_16x16x32_bf16(a0[f][0], b01[g][0], acc[f][g], 0,0,0);
        acc[f][g] = __builtin_amdgcn_mfma_f32_16x16x32_bf16(a0[f][1], b01[g][1], acc[f][g], 0,0,0);
      }
    __builtin_amdgcn_s_setprio(0);
    sbar();

    // ---- phase +1
#pragma unroll
    for (int g=0;g<2;g++){
      b23[g][0] = ldfrag(&Bs[(wn*64 + (g+2)*16 + ln)*64 + swr0*8]);
      b23[g][1] = ldfrag(&Bs[(wn*64 + (g+2)*16 + ln)*64 + swr1*8]);
    }
    sbar();
    __builtin_amdgcn_s_setprio(1);
#pragma unroll
    for (int f=0;f<4;f++)
#pragma unroll
      for (int g=0;g<2;g++){
        acc[f][g+2] = __builtin_amdgcn_mfma_f32_16x16x32_bf16(a0[f][0], b23[g][0], acc[f][g+2], 0,0,0);
        acc[f][g+2] = __builtin_amdgcn_mfma_f32_16x16x32_bf16(a0[f][1], b23[g][1], acc[f][g+2], 0,0,0);
      }
    __builtin_amdgcn_s_setprio(0);
    sbar();

    // ---- phase +2
#pragma unroll
    for (int f=0;f<4;f++){
      a4[f][0] = ldfrag(&As[(wm*128 + (f+4)*16 + ln)*64 + swr0*8]);
      a4[f][1] = ldfrag(&As[(wm*128 + (f+4)*16 + ln)*64 + swr1*8]);
    }
    if (T+2 < 32) STAGEP(b, 1, 0, T+2);
    sbar();
    __builtin_amdgcn_s_setprio(1);
#pragma unroll
    for (int f=0;f<4;f++)
#pragma unroll
      for (int g=0;g<2;g++){
        acc[f+4][g+2] = __builtin_amdgcn_mfma_f32_16x16x32_bf16(a4[f][0], b23[g][0], acc[f+4][g+2], 0,0,0);
        acc[f+4][g+2] = __builtin_amdgcn_mfma_f32_16x16x32_bf16(a4[f][1], b23[g][1], acc[f+4][g+2], 0,0,0);
      }
    __builtin_amdgcn_s_setprio(0);
    sbar();

    // ---- phase +3
    if (T+2 < 32){ STAGEP(b, 1, 1, T+2); STAGEP(b, 0, 0, T+2); }
    if (T >= 30) asm volatile("s_waitcnt vmcnt(0)" ::: "memory");
    else         asm volatile("s_waitcnt vmcnt(6)" ::: "memory");
    sbar();
    __builtin_amdgcn_s_setprio(1);
#pragma unroll
    for (int f=0;f<4;f++)
#pragma unroll
      for (int g=0;g<2;g++){
        acc[f+4][g] = __builtin_amdgcn_mfma_f32_16x16x32_bf16(a4[f][0], b01[g][0], acc[f+4][g], 0,0,0);
        acc[f+4][g] = __builtin_amdgcn_mfma_f32_16x16x32_bf16(a4[f][1], b01[g][1], acc[f+4][g], 0,0,0);
      }
    __builtin_amdgcn_s_setprio(0);
    sbar();
  }
#undef STAGEP

  // epilogue: fp32 out [8192][2048]
  const int m_base = by*256 + wm*128;
#pragma unroll
  for (int g=0; g<4; ++g){
    const int ncol = bx*256 + wn*64 + g*16 + ln;
    const float bv = bias[ncol];
#pragma unroll
    for (int f=0; f<8; ++f){
      const int m0 = m_base + f*16 + lq*4;
      float* op = outp + (size_t)m0*2048 + ncol;
#pragma unroll
      for (int r=0;r<4;++r)
        op[(size_t)r*2048] = acc[f][g][r] + bv;
    }
  }
}

// ---------------- QKV GEMM, fallback: A = x fp32 (cvt in staging). ----------
__global__ __launch_bounds__(256,2) void gemm_qkv_f32(
    const float* __restrict__ X, const u16* __restrict__ Wt, const float* __restrict__ bias,
    u16* __restrict__ qb, u16* __restrict__ kb, u16* __restrict__ vb)
{
  __shared__ u16 As[128*32];
  __shared__ u16 Bs[128*32];
  const int t = threadIdx.x;
  const int bx = blockIdx.x, by = blockIdx.y;
  const int lane = t & 63, wv = t >> 6;
  const int lq = lane >> 4, ln = lane & 15;
  const int wm = wv >> 1, wn = wv & 1;

  const int ar = t >> 1, ah = t & 1;
  const float* Ap = X + (size_t)(by*128 + ar)*2048 + ah*16;
  u16* AsW = &As[ar*32 + ah*16];

  const int c0 = t, c1 = 256 + t;
  const u16* Bp0 = Wt + (size_t)(bx*128 + (c0 >> 2))*2048 + (c0 & 3)*8;
  const u16* Bp1 = Wt + (size_t)(bx*128 + (c1 >> 2))*2048 + (c1 & 3)*8;
  const u16* BsW0 = &Bs[(wv*64)*8];
  const u16* BsW1 = &Bs[(256 + wv*64)*8];

  const f32x4 fz = {0.f,0.f,0.f,0.f};
  f32x4 acc[4][4];
#pragma unroll
  for (int i=0;i<4;i++)
#pragma unroll
    for (int j=0;j<4;j++) acc[i][j] = fz;

  for (int kt = 0; kt < 64; ++kt){
    float4 a0 = *(const float4*)(Ap);
    float4 a1 = *(const float4*)(Ap + 4);
    float4 a2 = *(const float4*)(Ap + 8);
    float4 a3 = *(const float4*)(Ap + 12);
    Ap += 32;
    __syncthreads();
    uint4 w0, w1;
    w0.x = pk2(a0.x,a0.y); w0.y = pk2(a0.z,a0.w);
    w0.z = pk2(a1.x,a1.y); w0.w = pk2(a1.z,a1.w);
    w1.x = pk2(a2.x,a2.y); w1.y = pk2(a2.z,a2.w);
    w1.z = pk2(a3.x,a3.y); w1.w = pk2(a3.z,a3.w);
    *(uint4*)(AsW) = w0; *(uint4*)(AsW + 8) = w1;
    glds16(Bp0, BsW0);
    glds16(Bp1, BsW1);
    Bp0 += 32; Bp1 += 32;
    __syncthreads();
    bf16x8 af[4], bf[4];
#pragma unroll
    for (int i=0;i<4;i++) af[i] = ldfrag(&As[(wm*64 + i*16 + ln)*32 + lq*8]);
#pragma unroll
    for (int j=0;j<4;j++) bf[j] = ldfrag(&Bs[(wn*64 + j*16 + ln)*32 + lq*8]);
#pragma unroll
    for (int i=0;i<4;i++)
#pragma unroll
      for (int j=0;j<4;j++)
        acc[i][j] = __builtin_amdgcn_mfma_f32_16x16x32_bf16(af[i], bf[j], acc[i][j], 0,0,0);
  }
  qkv_epilogue(acc, bias, bx, by, wm, wn, lq, ln, qb, kb, vb);
}

// ---------------- flash attention (unchanged from R10) ----------------------
__global__ __launch_bounds__(256,2) void attn_fwd(
    u16* qy, const u16* __restrict__ kk, const u16* __restrict__ vv)
{
  __shared__ u16 Ks[64*128];                   // [key][d], swizzled
  __shared__ u16 Vt[128*64];                   // [d][key], swizzled
  __shared__ u16 Ps[4*32*64];                  // per-wave P strip, swizzled
  const int qt = 7 - blockIdx.x, bh = blockIdx.y;
  const int t = threadIdx.x;
  const int lane = t & 63, wv = t >> 6;
  const int lq = lane >> 4, ln = lane & 15;

  bf16x8 qf[2][4];                             // A-frag: m=lane&15, k=quad*8+j
#pragma unroll
  for (int i=0;i<2;i++)
#pragma unroll
    for (int kc=0;kc<4;kc++){
      int qrow = qt*128 + wv*32 + i*16 + ln;
      qf[i][kc] = ldfrag(&qy[((size_t)bh*T_ + qrow)*HD + kc*32 + lq*8]);
    }

  const f32x4 fz = {0.f,0.f,0.f,0.f};
  f32x4 o[2][8];
#pragma unroll
  for (int i=0;i<2;i++)
#pragma unroll
    for (int jd=0;jd<8;jd++) o[i][jd] = fz;
  float mi[2][4], li[2][4];
#pragma unroll
  for (int i=0;i<2;i++)
#pragma unroll
    for (int r=0;r<4;r++){ mi[i][r] = -1e30f; li[i][r] = 0.f; }

  const float scale = 0.08838834764831843f;    // 1/sqrt(128)
  const int kr = t & 63, dbase = (t >> 6)*32;  // V-transpose stage mapping
  const int nkt = 2*qt + 2;                    // causal: keys < (qt+1)*128

  uint4 kreg[4];
  uint4 vreg[4];
  {
    const uint4* ksrc = (const uint4*)(kk + (size_t)bh*T_*HD);
#pragma unroll
    for (int ii=0; ii<4; ++ii) kreg[ii] = ksrc[t + ii*256];
#pragma unroll
    for (int ch=0; ch<4; ++ch)
      vreg[ch] = *(const uint4*)&vv[((size_t)bh*T_ + kr)*HD + dbase + ch*8];
  }

  for (int kt = 0; kt < nkt; ++kt){
    __syncthreads();                           // prior iter done reading Ks/Vt
    uint4* kdst = (uint4*)Ks;
#pragma unroll
    for (int ii=0; ii<4; ++ii){
      const int c = t + ii*256;                // chunk: row c>>4, slot c&15
      kdst[(c & ~15) | ((c & 15) ^ ((c >> 4) & 7))] = kreg[ii];
    }
#pragma unroll
    for (int ch=0; ch<4; ++ch){
      const u16* e = (const u16*)&vreg[ch];
#pragma unroll
      for (int j=0; j<8; ++j){
        const int d = dbase + ch*8 + j;
        Vt[d*64 + (kr ^ ((d & 7) << 3))] = e[j]; // distinct cols/lane: free
      }
    }
    __syncthreads();

    {
      const int ktn = (kt+1 < nkt) ? kt+1 : kt;   // last iter: harmless reload
      const uint4* ksrc = (const uint4*)(kk + ((size_t)bh*T_ + ktn*64)*HD);
#pragma unroll
      for (int ii=0; ii<4; ++ii) kreg[ii] = ksrc[t + ii*256];
#pragma unroll
      for (int ch=0; ch<4; ++ch)
        vreg[ch] = *(const uint4*)&vv[((size_t)bh*T_ + ktn*64 + kr)*HD + dbase + ch*8];
    }

    // waves whose whole q-range is masked for this k-tile skip compute
    const bool active = (kt*64) <= (qt*128 + wv*32 + 31);
    if (active){

    // S = Q K^T
    f32x4 s[2][4];
#pragma unroll
    for (int i=0;i<2;i++)
#pragma unroll
      for (int j=0;j<4;j++) s[i][j] = fz;
    __builtin_amdgcn_s_setprio(1);
#pragma unroll
    for (int j=0;j<4;j++){
      bf16x8 kf[4];                            // B-frag: n=key, k=d
      const int krow = j*16 + ln;
      const int ksw = (krow & 7) << 3;
#pragma unroll
      for (int kc=0;kc<4;kc++)
        kf[kc] = ldfrag(&Ks[krow*128 + ((kc*32 + lq*8) ^ ksw)]);
#pragma unroll
      for (int i=0;i<2;i++)
#pragma unroll
        for (int kc=0;kc<4;kc++)
          s[i][j] = __builtin_amdgcn_mfma_f32_16x16x32_bf16(qf[i][kc], kf[kc], s[i][j], 0,0,0);
    }
    __builtin_amdgcn_s_setprio(0);

    // scale + causal mask (C/D: row=quad*4+r, col=lane&15)
#pragma unroll
    for (int i=0;i<2;i++)
#pragma unroll
      for (int j=0;j<4;j++)
#pragma unroll
        for (int r=0;r<4;r++){
          int qg = qt*128 + wv*32 + i*16 + lq*4 + r;
          int kg = kt*64 + j*16 + ln;
          float sv = s[i][j][r]*scale;
          s[i][j][r] = (kg > qg) ? -1e30f : sv;
        }

    // online softmax with defer-max (THR=8)
    float mxv[2][4];
#pragma unroll
    for (int i=0;i<2;i++)
#pragma unroll
      for (int r=0;r<4;r++){
        float mx = fmaxf(fmaxf(s[i][0][r], s[i][1][r]), fmaxf(s[i][2][r], s[i][3][r]));
        mx = fmaxf(mx, __shfl_xor(mx, 1));
        mx = fmaxf(mx, __shfl_xor(mx, 2));
        mx = fmaxf(mx, __shfl_xor(mx, 4));
        mx = fmaxf(mx, __shfl_xor(mx, 8));
        mxv[i][r] = mx;
      }
    bool ok = true;
#pragma unroll
    for (int i=0;i<2;i++)
#pragma unroll
      for (int r=0;r<4;r++) ok = ok && (mxv[i][r] <= mi[i][r] + 8.0f);
    if (!__all((int)ok)){
#pragma unroll
      for (int i=0;i<2;i++)
#pragma unroll
        for (int r=0;r<4;r++){
          float mnew = fmaxf(mi[i][r], mxv[i][r]);
          float alpha = __expf(mi[i][r] - mnew);
          li[i][r] *= alpha;
          mi[i][r] = mnew;
#pragma unroll
          for (int jd=0;jd<8;jd++) o[i][jd][r] *= alpha;
        }
    }
#pragma unroll
    for (int i=0;i<2;i++)
#pragma unroll
      for (int r=0;r<4;r++){
        float rs = 0.f;
#pragma unroll
        for (int j=0;j<4;j++){
          float p = __expf(s[i][j][r] - mi[i][r]);   // bounded by e^8
          s[i][j][r] = p; rs += p;
        }
        rs += __shfl_xor(rs, 1); rs += __shfl_xor(rs, 2);
        rs += __shfl_xor(rs, 4); rs += __shfl_xor(rs, 8);
        li[i][r] += rs;
      }

    // P: C-layout -> per-wave LDS strip (swizzled) -> A-layout frags
#pragma unroll
    for (int i=0;i<2;i++)
#pragma unroll
      for (int j=0;j<4;j++)
#pragma unroll
        for (int r=0;r<4;r++){
          const int rr = i*16 + lq*4 + r;
          Ps[wv*2048 + rr*64 + ((j*16 + ln) ^ ((rr & 7) << 3))] = f2b(s[i][j][r]);
        }

    bf16x8 pf[2][2];
#pragma unroll
    for (int i=0;i<2;i++){
      const int prow = i*16 + ln;
      const int psw = (prow & 7) << 3;
#pragma unroll
      for (int kc=0;kc<2;kc++)
        pf[i][kc] = ldfrag(&Ps[wv*2048 + prow*64 + ((kc*32 + lq*8) ^ psw)]);
    }
    __builtin_amdgcn_s_setprio(1);
#pragma unroll
    for (int jd=0;jd<8;jd++){
      const int vrow = jd*16 + ln;
      const int vsw = (vrow & 7) << 3;
#pragma unroll
      for (int kc=0;kc<2;kc++){
        bf16x8 vf = ldfrag(&Vt[vrow*64 + ((kc*32 + lq*8) ^ vsw)]);
#pragma unroll
        for (int i=0;i<2;i++)
          o[i][jd] = __builtin_amdgcn_mfma_f32_16x16x32_bf16(pf[i][kc], vf, o[i][jd], 0,0,0);
      }
    }
    __builtin_amdgcn_s_setprio(0);

    } // active
  }

  // epilogue: y over own Q tile, head-major [BH][T][HD]
#pragma unroll
  for (int i=0;i<2;i++)
#pragma unroll
    for (int r=0;r<4;r++){
      float inv = 1.f / li[i][r];
      int row = qt*128 + wv*32 + i*16 + lq*4 + r;
#pragma unroll
      for (int jd=0;jd<8;jd++)
        qy[((size_t)bh*T_ + row)*HD + jd*16 + ln] = f2b(o[i][jd][r] * inv);
    }
}

extern "C" void kernel_launch(void* const* d_in, const int* in_sizes, int n_in,
                              void* d_out, int out_size, void* d_ws, size_t ws_size,
                              hipStream_t stream)
{
  const float* x      = (const float*)d_in[0];   // [8192][2048] fp32
  const float* W_attn = (const float*)d_in[1];   // [2048][6144] fp32
  const float* b_attn = (const float*)d_in[2];   // [6144] fp32
  const float* W_proj = (const float*)d_in[3];   // [2048][2048] fp32
  const float* b_proj = (const float*)d_in[4];   // [2048] fp32
  float* out = (float*)d_out;                    // [8192][2048] fp32

  u16* Wat = (u16*)d_ws;                         // [6144][2048] bf16 = W_attn^T
  u16* Wpt = Wat + (size_t)6144*2048;            // [2048][2048] bf16 = W_proj^T
  u16* qb  = Wpt + (size_t)2048*2048;            // Q bf16, then y bf16
  u16* xb  = qb  + (size_t)BH*T_*HD;             // x bf16 (only if ws >= 96 MiB)
  u16* kb  = (u16*)d_out;                        // K bf16 (d_out low half)
  u16* vb  = kb + (size_t)BH*T_*HD;              // V bf16 (d_out high half)

  const size_t need = ((size_t)6144*2048 + (size_t)2048*2048
                       + 2*(size_t)BH*T_*HD) * sizeof(u16);   // 96 MiB

  hipLaunchKernelGGL(transpose_cvt, dim3(96,32,1), dim3(256,1,1), 0, stream,
                     W_attn, Wat, 2048, 6144);
  hipLaunchKernelGGL(transpose_cvt, dim3(32,32,1), dim3(256,1,1), 0, stream,
                     W_proj, Wpt, 2048, 2048);
  if (ws_size >= need){
    hipLaunchKernelGGL(cvt_bf16, dim3(1024,1,1), dim3(256,1,1), 0, stream,
                       (const float4*)x, (ushort4*)xb, (B_*T_*C_)/4);
    hipLaunchKernelGGL(gemm_qkv_8p, dim3(768,1,1), dim3(512,1,1), 0, stream,
                       xb, Wat, b_attn, qb, kb, vb);
  } else {
    hipLaunchKernelGGL(gemm_qkv_f32, dim3(48,64,1), dim3(256,1,1), 0, stream,
                       x, Wat, b_attn, qb, kb, vb);
  }
  hipLaunchKernelGGL(attn_fwd, dim3(8,BH,1), dim3(256,1,1), 0, stream,
                     qb, kb, vb);
  hipLaunchKernelGGL(gemm_proj_8p, dim3(256,1,1), dim3(512,1,1), 0, stream,
                     qb, Wpt, b_proj, out);
}

// Round 7
// 598.308 us; speedup vs baseline: 1.0347x; 1.0347x over previous
//
#include <hip/hip_runtime.h>
#include <hip/hip_bf16.h>

// CausalSelfAttention: B=8 T=1024 C=2048 NH=16 HD=128. FP32 I/O, bf16 MFMA.
// R12: GEMMs reverted to the R10-proven 8-phase schedule (R11's rebalance
// regressed 221->240us: moved stages shortened load-hiding distance). New:
// (1) attn K/V double-buffered -> ONE barrier per k-tile (WAR proof: reads of
// buf b from iter kt-2 are lgkm-drained before barrier(kt-1)); LDS 80KiB,
// still 2 blocks/CU. (2) pre-kernels fused into one launch (prep): z=0
// W_attn transpose, z=1 W_proj transpose + x->bf16 cvt in spare blocks.
// ws: Wat^T 24M | Wpt^T 8M | Q 32M (y overwrites Q after attn) | [xb 32M].
// d_out: K bf16 | V bf16 until proj GEMM overwrites with fp32 result.

typedef unsigned short u16;
typedef __bf16 bf16x8 __attribute__((ext_vector_type(8)));
typedef float f32x4 __attribute__((ext_vector_type(4)));

#define B_ 8
#define T_ 1024
#define C_ 2048
#define NH 16
#define HD 128
#define BH (B_*NH)

__device__ __forceinline__ u16 f2b(float f){
  __bf16 h = (__bf16)f; return __builtin_bit_cast(u16, h);   // RNE
}
__device__ __forceinline__ unsigned pk2(float x, float y){
  return (unsigned)f2b(x) | ((unsigned)f2b(y) << 16);
}
__device__ __forceinline__ bf16x8 ldfrag(const u16* p){
  uint4 u = *(const uint4*)p; return __builtin_bit_cast(bf16x8, u);
}
__device__ __forceinline__ void glds16(const u16* g, const u16* l){
  __builtin_amdgcn_global_load_lds(
      (const __attribute__((address_space(1))) void*)g,
      (__attribute__((address_space(3))) void*)l, 16, 0, 0);
}
__device__ __forceinline__ void sbar(){
  __builtin_amdgcn_sched_barrier(0);
  __builtin_amdgcn_s_barrier();
  __builtin_amdgcn_sched_barrier(0);
}

// ---------------- fused pre-pass: W transposes + x cvt ----------------------
// grid (96,32,2). z=0: W_attn [2048][6144] -> Wat [6144][2048].
// z=1, bx<32: W_proj -> Wpt. z=1, bx>=32: x fp32 -> xb bf16 (2048 blocks).
__global__ __launch_bounds__(256) void prep(
    const float* __restrict__ W_attn, u16* __restrict__ Wat,
    const float* __restrict__ W_proj, u16* __restrict__ Wpt,
    const float4* __restrict__ x4, ushort4* __restrict__ xb4, int do_cvt)
{
  __shared__ u16 tile[64][65];
  const int t = threadIdx.x;
  const int z = blockIdx.z;
  if (z == 1 && blockIdx.x >= 32){
    if (!do_cvt) return;
    const int n4 = (B_*T_*C_)/4;
    int i = ((blockIdx.x - 32)*32 + blockIdx.y)*256 + t;
    const int stride = 2048*256;
    for (; i < n4; i += stride){
      float4 f = x4[i];
      ushort4 o; o.x = f2b(f.x); o.y = f2b(f.y); o.z = f2b(f.z); o.w = f2b(f.w);
      xb4[i] = o;
    }
    return;
  }
  const float* in = (z == 0) ? W_attn : W_proj;
  u16* outp       = (z == 0) ? Wat    : Wpt;
  const int R = 2048, C = (z == 0) ? 6144 : 2048;
  const int r0 = blockIdx.y * 64, c0 = blockIdx.x * 64;
#pragma unroll
  for (int ii = 0; ii < 16; ++ii){
    int idx = t + ii*256; int r = idx >> 6, c = idx & 63;
    tile[r][c] = f2b(in[(size_t)(r0 + r)*C + c0 + c]);
  }
  __syncthreads();
#pragma unroll
  for (int ii = 0; ii < 16; ++ii){
    int idx = t + ii*256; int r = idx >> 6, c = idx & 63;
    outp[(size_t)(c0 + r)*R + r0 + c] = tile[c][r];
  }
}

// ---------------- QKV epilogue for 128-tile fallback path -------------------
__device__ __forceinline__ void qkv_epilogue(
    const f32x4 acc[4][4], const float* bias, int bx, int by,
    int wm, int wn, int lq, int ln,
    u16* qb, u16* kb, u16* vb)
{
  const int tensor = bx >> 4, h = bx & 15, b = by >> 3, t0 = (by & 7)*128;
  u16* tb = tensor==0 ? qb : (tensor==1 ? kb : vb);
  u16* op = tb + ((size_t)(b*NH + h)*T_ + t0)*HD;
#pragma unroll
  for (int j=0;j<4;j++){
    const float bv = bias[bx*128 + wn*64 + j*16 + ln];
    const int n = wn*64 + j*16 + ln;
#pragma unroll
    for (int i=0;i<4;i++){
      const int m0 = wm*64 + i*16 + lq*4;      // C/D: row = quad*4 + reg
#pragma unroll
      for (int r=0;r<4;r++)
        op[(size_t)(m0 + r)*HD + n] = f2b(acc[i][j][r] + bv);
    }
  }
}

// ---------------- QKV GEMM, 256x256 8-phase (R10-proven schedule) -----------
__global__ __launch_bounds__(512,2) void gemm_qkv_8p(
    const u16* __restrict__ Xb, const u16* __restrict__ Wt,
    const float* __restrict__ bias,
    u16* __restrict__ qb, u16* __restrict__ kb, u16* __restrict__ vb)
{
  __shared__ u16 lds[2][2][256*64];            // [buf][A/B][row][k] 128 KiB
  const int t = threadIdx.x;                   // 0..511
  const int lane = t & 63, wid = t >> 6;       // 8 waves: 2M x 4N
  const int lq = lane >> 4, ln = lane & 15;
  const int wm = wid >> 2, wn = wid & 3;

  // XCD-aware swizzle (768 blocks, 768%8==0 -> simple form is bijective)
  const int bid0 = blockIdx.x;
  const int bid = (bid0 & 7)*96 + (bid0 >> 3);
  const int bx = bid % 24, by = bid / 24;      // bx: N/256, by: M/256

  const int rl  = (wid << 4) + (lane >> 3);    // q=0 local row (0..127)
  const int sw0 = (lane & 7) ^ (rl & 7);
  const u16* Ag = Xb + ((size_t)(by*256) + rl)*2048;
  const u16* Bg = Wt + ((size_t)(bx*256) + rl)*2048;
  const size_t q0off = (size_t)sw0*8;
  const size_t q1off = (size_t)8*2048 + (size_t)sw0*8;   // (rl+8)&7 == rl&7

#define STAGE(buf_, op_, h_, T_) do { \
    const u16* s_ = (op_ ? Bg : Ag) + (size_t)(h_)*(128*2048) + (size_t)(T_)*64; \
    const u16* d_ = &lds[buf_][op_][(((h_)*128) + (wid<<4))*64]; \
    glds16(s_ + q0off, d_); \
    glds16(s_ + q1off, d_ + 8*64); \
  } while(0)

  const int swr0 = (0*4 + lq) ^ (ln & 7);
  const int swr1 = (1*4 + lq) ^ (ln & 7);

  const f32x4 fz = {0.f,0.f,0.f,0.f};
  f32x4 acc[8][4];
#pragma unroll
  for (int f=0;f<8;f++)
#pragma unroll
    for (int g=0;g<4;g++) acc[f][g] = fz;

  // prologue: tile0 fully + tile1's Bhi,Blo,Ahi (Alo(1) comes at (0,+0))
  STAGE(0,0,0,0); STAGE(0,0,1,0); STAGE(0,1,0,0); STAGE(0,1,1,0);
  STAGE(1,1,0,1); STAGE(1,1,1,1); STAGE(1,0,0,1);
  asm volatile("s_waitcnt vmcnt(6)" ::: "memory");   // tile0 landed
  sbar();

  for (int T = 0; T < 32; ++T){
    const int b = T & 1;
    const u16* As = lds[b][0];
    const u16* Bs = lds[b][1];
    bf16x8 a0[4][2], a4[4][2], bfr[4][2];

    // ---- phase +0: read A frags 0-3 + all B frags; stage Alo(T+1)
#pragma unroll
    for (int f=0;f<4;f++){
      a0[f][0]  = ldfrag(&As[(wm*128 + f*16 + ln)*64 + swr0*8]);
      a0[f][1]  = ldfrag(&As[(wm*128 + f*16 + ln)*64 + swr1*8]);
      bfr[f][0] = ldfrag(&Bs[(wn*64  + f*16 + ln)*64 + swr0*8]);
      bfr[f][1] = ldfrag(&Bs[(wn*64  + f*16 + ln)*64 + swr1*8]);
    }
    if (T+1 < 32) STAGE(b^1, 0, 1, T+1);
    sbar();
    __builtin_amdgcn_s_setprio(1);
#pragma unroll
    for (int f=0;f<4;f++)
#pragma unroll
      for (int g=0;g<2;g++){
        acc[f][g] = __builtin_amdgcn_mfma_f32_16x16x32_bf16(a0[f][0], bfr[g][0], acc[f][g], 0,0,0);
        acc[f][g] = __builtin_amdgcn_mfma_f32_16x16x32_bf16(a0[f][1], bfr[g][1], acc[f][g], 0,0,0);
      }
    __builtin_amdgcn_s_setprio(0);
    sbar();

    // ---- phase +1: read A frags 4-7; stage Bhi(T+2)
#pragma unroll
    for (int f=0;f<4;f++){
      a4[f][0] = ldfrag(&As[(wm*128 + (f+4)*16 + ln)*64 + swr0*8]);
      a4[f][1] = ldfrag(&As[(wm*128 + (f+4)*16 + ln)*64 + swr1*8]);
    }
    if (T+2 < 32) STAGE(b, 1, 0, T+2);
    sbar();
    __builtin_amdgcn_s_setprio(1);
#pragma unroll
    for (int f=0;f<4;f++)
#pragma unroll
      for (int g=0;g<2;g++){
        acc[f+4][g] = __builtin_amdgcn_mfma_f32_16x16x32_bf16(a4[f][0], bfr[g][0], acc[f+4][g], 0,0,0);
        acc[f+4][g] = __builtin_amdgcn_mfma_f32_16x16x32_bf16(a4[f][1], bfr[g][1], acc[f+4][g], 0,0,0);
      }
    __builtin_amdgcn_s_setprio(0);
    sbar();

    // ---- phase +2: no reads; stage Blo(T+2)
    if (T+2 < 32) STAGE(b, 1, 1, T+2);
    sbar();
    __builtin_amdgcn_s_setprio(1);
#pragma unroll
    for (int f=0;f<4;f++)
#pragma unroll
      for (int g=2;g<4;g++){
        acc[f+4][g] = __builtin_amdgcn_mfma_f32_16x16x32_bf16(a4[f][0], bfr[g][0], acc[f+4][g], 0,0,0);
        acc[f+4][g] = __builtin_amdgcn_mfma_f32_16x16x32_bf16(a4[f][1], bfr[g][1], acc[f+4][g], 0,0,0);
      }
    __builtin_amdgcn_s_setprio(0);
    sbar();

    // ---- phase +3: no reads; stage Ahi(T+2); counted vmcnt
    if (T+2 < 32) STAGE(b, 0, 0, T+2);
    if (T >= 30) asm volatile("s_waitcnt vmcnt(0)" ::: "memory");
    else         asm volatile("s_waitcnt vmcnt(6)" ::: "memory");
    sbar();
    __builtin_amdgcn_s_setprio(1);
#pragma unroll
    for (int f=0;f<4;f++)
#pragma unroll
      for (int g=2;g<4;g++){
        acc[f][g] = __builtin_amdgcn_mfma_f32_16x16x32_bf16(a0[f][0], bfr[g][0], acc[f][g], 0,0,0);
        acc[f][g] = __builtin_amdgcn_mfma_f32_16x16x32_bf16(a0[f][1], bfr[g][1], acc[f][g], 0,0,0);
      }
    __builtin_amdgcn_s_setprio(0);
    sbar();
  }
#undef STAGE

  // epilogue: scatter to Q/K/V [BH][T][HD]
  const int tensor = bx >> 3;
  u16* tb = tensor==0 ? qb : (tensor==1 ? kb : vb);
  const int m_base = by*256 + wm*128;
#pragma unroll
  for (int g=0; g<4; ++g){
    const int ncol = (bx & 7)*256 + wn*64 + g*16 + ln;   // 0..2047 in tensor
    const float bv = bias[tensor*2048 + ncol];
    const int h = ncol >> 7, d = ncol & 127;
#pragma unroll
    for (int f=0; f<8; ++f){
      const int m0 = m_base + f*16 + lq*4;
      const int bb = m0 >> 10, tt = m0 & 1023;           // rows m0..m0+3 same b
      u16* op = tb + ((size_t)(bb*NH + h)*T_ + tt)*HD + d;
#pragma unroll
      for (int r=0;r<4;++r)
        op[(size_t)r*HD] = f2b(acc[f][g][r] + bv);
    }
  }
}

// ---------------- proj GEMM, 256x256 8-phase (R10-proven schedule) ----------
__global__ __launch_bounds__(512,2) void gemm_proj_8p(
    const u16* __restrict__ Y, const u16* __restrict__ Wt,
    const float* __restrict__ bias, float* __restrict__ outp)
{
  __shared__ u16 lds[2][2][256*64];            // [buf][A/B][row][k] 128 KiB
  const int t = threadIdx.x;
  const int lane = t & 63, wid = t >> 6;
  const int lq = lane >> 4, ln = lane & 15;
  const int wm = wid >> 2, wn = wid & 3;

  // 256 blocks, 256%8==0 -> bijective XCD swizzle
  const int bid0 = blockIdx.x;
  const int bid = (bid0 & 7)*32 + (bid0 >> 3);
  const int bx = bid & 7, by = bid >> 3;       // bx: N/256 (8), by: M/256 (32)

  const int rl  = (wid << 4) + (lane >> 3);
  const int sw0 = (lane & 7) ^ (rl & 7);
  const u16* Bg = Wt + ((size_t)(bx*256) + rl)*2048;
  const size_t bq0 = (size_t)sw0*8;
  const size_t arow0 = ((size_t)(by >> 2)*16)*1024 + (size_t)(by & 3)*256 + rl;

#define STAGEP(buf_, op_, h_, Tt_) do { \
    const u16* d_ = &lds[buf_][op_][(((h_)*128) + (wid<<4))*64]; \
    if (op_){ \
      const u16* s_ = Bg + (size_t)(h_)*(128*2048) + (size_t)(Tt_)*64; \
      glds16(s_ + bq0, d_); \
      glds16(s_ + (size_t)8*2048 + bq0, d_ + 8*64); \
    } else { \
      const u16* s_ = Y + (arow0 + (size_t)((Tt_) >> 1)*1024 + (size_t)(h_)*128)*128 \
                        + ((Tt_) & 1)*64 + sw0*8; \
      glds16(s_, d_); \
      glds16(s_ + 8*128, d_ + 8*64); \
    } \
  } while(0)

  const int swr0 = (0*4 + lq) ^ (ln & 7);
  const int swr1 = (1*4 + lq) ^ (ln & 7);

  const f32x4 fz = {0.f,0.f,0.f,0.f};
  f32x4 acc[8][4];
#pragma unroll
  for (int f=0;f<8;f++)
#pragma unroll
    for (int g=0;g<4;g++) acc[f][g] = fz;

  STAGEP(0,0,0,0); STAGEP(0,0,1,0); STAGEP(0,1,0,0); STAGEP(0,1,1,0);
  STAGEP(1,1,0,1); STAGEP(1,1,1,1); STAGEP(1,0,0,1);
  asm volatile("s_waitcnt vmcnt(6)" ::: "memory");
  sbar();

  for (int T = 0; T < 32; ++T){
    const int b = T & 1;
    const u16* As = lds[b][0];
    const u16* Bs = lds[b][1];
    bf16x8 a0[4][2], a4[4][2], bfr[4][2];

#pragma unroll
    for (int f=0;f<4;f++){
      a0[f][0]  = ldfrag(&As[(wm*128 + f*16 + ln)*64 + swr0*8]);
      a0[f][1]  = ldfrag(&As[(wm*128 + f*16 + ln)*64 + swr1*8]);
      bfr[f][0] = ldfrag(&Bs[(wn*64  + f*16 + ln)*64 + swr0*8]);
      bfr[f][1] = ldfrag(&Bs[(wn*64  + f*16 + ln)*64 + swr1*8]);
    }
    if (T+1 < 32) STAGEP(b^1, 0, 1, T+1);
    sbar();
    __builtin_amdgcn_s_setprio(1);
#pragma unroll
    for (int f=0;f<4;f++)
#pragma unroll
      for (int g=0;g<2;g++){
        acc[f][g] = __builtin_amdgcn_mfma_f32_16x16x32_bf16(a0[f][0], bfr[g][0], acc[f][g], 0,0,0);
        acc[f][g] = __builtin_amdgcn_mfma_f32_16x16x32_bf16(a0[f][1], bfr[g][1], acc[f][g], 0,0,0);
      }
    __builtin_amdgcn_s_setprio(0);
    sbar();

#pragma unroll
    for (int f=0;f<4;f++){
      a4[f][0] = ldfrag(&As[(wm*128 + (f+4)*16 + ln)*64 + swr0*8]);
      a4[f][1] = ldfrag(&As[(wm*128 + (f+4)*16 + ln)*64 + swr1*8]);
    }
    if (T+2 < 32) STAGEP(b, 1, 0, T+2);
    sbar();
    __builtin_amdgcn_s_setprio(1);
#pragma unroll
    for (int f=0;f<4;f++)
#pragma unroll
      for (int g=0;g<2;g++){
        acc[f+4][g] = __builtin_amdgcn_mfma_f32_16x16x32_bf16(a4[f][0], bfr[g][0], acc[f+4][g], 0,0,0);
        acc[f+4][g] = __builtin_amdgcn_mfma_f32_16x16x32_bf16(a4[f][1], bfr[g][1], acc[f+4][g], 0,0,0);
      }
    __builtin_amdgcn_s_setprio(0);
    sbar();

    if (T+2 < 32) STAGEP(b, 1, 1, T+2);
    sbar();
    __builtin_amdgcn_s_setprio(1);
#pragma unroll
    for (int f=0;f<4;f++)
#pragma unroll
      for (int g=2;g<4;g++){
        acc[f+4][g] = __builtin_amdgcn_mfma_f32_16x16x32_bf16(a4[f][0], bfr[g][0], acc[f+4][g], 0,0,0);
        acc[f+4][g] = __builtin_amdgcn_mfma_f32_16x16x32_bf16(a4[f][1], bfr[g][1], acc[f+4][g], 0,0,0);
      }
    __builtin_amdgcn_s_setprio(0);
    sbar();

    if (T+2 < 32) STAGEP(b, 0, 0, T+2);
    if (T >= 30) asm volatile("s_waitcnt vmcnt(0)" ::: "memory");
    else         asm volatile("s_waitcnt vmcnt(6)" ::: "memory");
    sbar();
    __builtin_amdgcn_s_setprio(1);
#pragma unroll
    for (int f=0;f<4;f++)
#pragma unroll
      for (int g=2;g<4;g++){
        acc[f][g] = __builtin_amdgcn_mfma_f32_16x16x32_bf16(a0[f][0], bfr[g][0], acc[f][g], 0,0,0);
        acc[f][g] = __builtin_amdgcn_mfma_f32_16x16x32_bf16(a0[f][1], bfr[g][1], acc[f][g], 0,0,0);
      }
    __builtin_amdgcn_s_setprio(0);
    sbar();
  }
#undef STAGEP

  // epilogue: fp32 out [8192][2048]
  const int m_base = by*256 + wm*128;
#pragma unroll
  for (int g=0; g<4; ++g){
    const int ncol = bx*256 + wn*64 + g*16 + ln;
    const float bv = bias[ncol];
#pragma unroll
    for (int f=0; f<8; ++f){
      const int m0 = m_base + f*16 + lq*4;
      float* op = outp + (size_t)m0*2048 + ncol;
#pragma unroll
      for (int r=0;r<4;++r)
        op[(size_t)r*2048] = acc[f][g][r] + bv;
    }
  }
}

// ---------------- QKV GEMM, fallback: A = x fp32 (cvt in staging). ----------
__global__ __launch_bounds__(256,2) void gemm_qkv_f32(
    const float* __restrict__ X, const u16* __restrict__ Wt, const float* __restrict__ bias,
    u16* __restrict__ qb, u16* __restrict__ kb, u16* __restrict__ vb)
{
  __shared__ u16 As[128*32];
  __shared__ u16 Bs[128*32];
  const int t = threadIdx.x;
  const int bx = blockIdx.x, by = blockIdx.y;
  const int lane = t & 63, wv = t >> 6;
  const int lq = lane >> 4, ln = lane & 15;
  const int wm = wv >> 1, wn = wv & 1;

  const int ar = t >> 1, ah = t & 1;
  const float* Ap = X + (size_t)(by*128 + ar)*2048 + ah*16;
  u16* AsW = &As[ar*32 + ah*16];

  const int c0 = t, c1 = 256 + t;
  const u16* Bp0 = Wt + (size_t)(bx*128 + (c0 >> 2))*2048 + (c0 & 3)*8;
  const u16* Bp1 = Wt + (size_t)(bx*128 + (c1 >> 2))*2048 + (c1 & 3)*8;
  const u16* BsW0 = &Bs[(wv*64)*8];
  const u16* BsW1 = &Bs[(256 + wv*64)*8];

  const f32x4 fz = {0.f,0.f,0.f,0.f};
  f32x4 acc[4][4];
#pragma unroll
  for (int i=0;i<4;i++)
#pragma unroll
    for (int j=0;j<4;j++) acc[i][j] = fz;

  for (int kt = 0; kt < 64; ++kt){
    float4 a0 = *(const float4*)(Ap);
    float4 a1 = *(const float4*)(Ap + 4);
    float4 a2 = *(const float4*)(Ap + 8);
    float4 a3 = *(const float4*)(Ap + 12);
    Ap += 32;
    __syncthreads();
    uint4 w0, w1;
    w0.x = pk2(a0.x,a0.y); w0.y = pk2(a0.z,a0.w);
    w0.z = pk2(a1.x,a1.y); w0.w = pk2(a1.z,a1.w);
    w1.x = pk2(a2.x,a2.y); w1.y = pk2(a2.z,a2.w);
    w1.z = pk2(a3.x,a3.y); w1.w = pk2(a3.z,a3.w);
    *(uint4*)(AsW) = w0; *(uint4*)(AsW + 8) = w1;
    glds16(Bp0, BsW0);
    glds16(Bp1, BsW1);
    Bp0 += 32; Bp1 += 32;
    __syncthreads();
    bf16x8 af[4], bf[4];
#pragma unroll
    for (int i=0;i<4;i++) af[i] = ldfrag(&As[(wm*64 + i*16 + ln)*32 + lq*8]);
#pragma unroll
    for (int j=0;j<4;j++) bf[j] = ldfrag(&Bs[(wn*64 + j*16 + ln)*32 + lq*8]);
#pragma unroll
    for (int i=0;i<4;i++)
#pragma unroll
      for (int j=0;j<4;j++)
        acc[i][j] = __builtin_amdgcn_mfma_f32_16x16x32_bf16(af[i], bf[j], acc[i][j], 0,0,0);
  }
  qkv_epilogue(acc, bias, bx, by, wm, wn, lq, ln, qb, kb, vb);
}

// ---------------- flash attention: R12 = R10 + K/V double-buffer ------------
// ONE barrier per k-tile: write(buf b) at iter kt only conflicts with reads
// of b at iter kt-2, which each wave completed (lgkm-drained into MFMAs)
// before it passed barrier(kt-1). LDS 80KiB -> still 2 blocks/CU.
__global__ __launch_bounds__(256,2) void attn_fwd(
    u16* qy, const u16* __restrict__ kk, const u16* __restrict__ vv)
{
  __shared__ u16 Ks[2][64*128];                // [buf][key][d], swizzled
  __shared__ u16 Vt[2][128*64];                // [buf][d][key], swizzled
  __shared__ u16 Ps[4*32*64];                  // per-wave P strip, swizzled
  const int qt = 7 - blockIdx.x, bh = blockIdx.y;
  const int t = threadIdx.x;
  const int lane = t & 63, wv = t >> 6;
  const int lq = lane >> 4, ln = lane & 15;

  bf16x8 qf[2][4];                             // A-frag: m=lane&15, k=quad*8+j
#pragma unroll
  for (int i=0;i<2;i++)
#pragma unroll
    for (int kc=0;kc<4;kc++){
      int qrow = qt*128 + wv*32 + i*16 + ln;
      qf[i][kc] = ldfrag(&qy[((size_t)bh*T_ + qrow)*HD + kc*32 + lq*8]);
    }

  const f32x4 fz = {0.f,0.f,0.f,0.f};
  f32x4 o[2][8];
#pragma unroll
  for (int i=0;i<2;i++)
#pragma unroll
    for (int jd=0;jd<8;jd++) o[i][jd] = fz;
  float mi[2][4], li[2][4];
#pragma unroll
  for (int i=0;i<2;i++)
#pragma unroll
    for (int r=0;r<4;r++){ mi[i][r] = -1e30f; li[i][r] = 0.f; }

  const float scale = 0.08838834764831843f;    // 1/sqrt(128)
  const int kr = t & 63, dbase = (t >> 6)*32;  // V-transpose stage mapping
  const int nkt = 2*qt + 2;                    // causal: keys < (qt+1)*128

  uint4 kreg[4];
  uint4 vreg[4];
  {
    const uint4* ksrc = (const uint4*)(kk + (size_t)bh*T_*HD);
#pragma unroll
    for (int ii=0; ii<4; ++ii) kreg[ii] = ksrc[t + ii*256];
#pragma unroll
    for (int ch=0; ch<4; ++ch)
      vreg[ch] = *(const uint4*)&vv[((size_t)bh*T_ + kr)*HD + dbase + ch*8];
  }

  for (int kt = 0; kt < nkt; ++kt){
    const int b = kt & 1;
    // write staged regs into buffer b (safe: readers of b finished at kt-2,
    // drained before barrier(kt-1))
    uint4* kdst = (uint4*)Ks[b];
#pragma unroll
    for (int ii=0; ii<4; ++ii){
      const int c = t + ii*256;                // chunk: row c>>4, slot c&15
      kdst[(c & ~15) | ((c & 15) ^ ((c >> 4) & 7))] = kreg[ii];
    }
#pragma unroll
    for (int ch=0; ch<4; ++ch){
      const u16* e = (const u16*)&vreg[ch];
#pragma unroll
      for (int j=0; j<8; ++j){
        const int d = dbase + ch*8 + j;
        Vt[b][d*64 + (kr ^ ((d & 7) << 3))] = e[j]; // distinct cols/lane: free
      }
    }
    // issue next tile's loads (kreg/vreg already consumed above)
    {
      const int ktn = (kt+1 < nkt) ? kt+1 : kt;   // last iter: harmless reload
      const uint4* ksrc = (const uint4*)(kk + ((size_t)bh*T_ + ktn*64)*HD);
#pragma unroll
      for (int ii=0; ii<4; ++ii) kreg[ii] = ksrc[t + ii*256];
#pragma unroll
      for (int ch=0; ch<4; ++ch)
        vreg[ch] = *(const uint4*)&vv[((size_t)bh*T_ + ktn*64 + kr)*HD + dbase + ch*8];
    }
    __syncthreads();                           // buffer b fully written

    // waves whose whole q-range is masked for this k-tile skip compute
    const bool active = (kt*64) <= (qt*128 + wv*32 + 31);
    if (active){

    // S = Q K^T
    f32x4 s[2][4];
#pragma unroll
    for (int i=0;i<2;i++)
#pragma unroll
      for (int j=0;j<4;j++) s[i][j] = fz;
    __builtin_amdgcn_s_setprio(1);
#pragma unroll
    for (int j=0;j<4;j++){
      bf16x8 kf[4];                            // B-frag: n=key, k=d
      const int krow = j*16 + ln;
      const int ksw = (krow & 7) << 3;
#pragma unroll
      for (int kc=0;kc<4;kc++)
        kf[kc] = ldfrag(&Ks[b][krow*128 + ((kc*32 + lq*8) ^ ksw)]);
#pragma unroll
      for (int i=0;i<2;i++)
#pragma unroll
        for (int kc=0;kc<4;kc++)
          s[i][j] = __builtin_amdgcn_mfma_f32_16x16x32_bf16(qf[i][kc], kf[kc], s[i][j], 0,0,0);
    }
    __builtin_amdgcn_s_setprio(0);

    // scale + causal mask (C/D: row=quad*4+r, col=lane&15)
#pragma unroll
    for (int i=0;i<2;i++)
#pragma unroll
      for (int j=0;j<4;j++)
#pragma unroll
        for (int r=0;r<4;r++){
          int qg = qt*128 + wv*32 + i*16 + lq*4 + r;
          int kg = kt*64 + j*16 + ln;
          float sv = s[i][j][r]*scale;
          s[i][j][r] = (kg > qg) ? -1e30f : sv;
        }

    // online softmax with defer-max (THR=8)
    float mxv[2][4];
#pragma unroll
    for (int i=0;i<2;i++)
#pragma unroll
      for (int r=0;r<4;r++){
        float mx = fmaxf(fmaxf(s[i][0][r], s[i][1][r]), fmaxf(s[i][2][r], s[i][3][r]));
        mx = fmaxf(mx, __shfl_xor(mx, 1));
        mx = fmaxf(mx, __shfl_xor(mx, 2));
        mx = fmaxf(mx, __shfl_xor(mx, 4));
        mx = fmaxf(mx, __shfl_xor(mx, 8));
        mxv[i][r] = mx;
      }
    bool ok = true;
#pragma unroll
    for (int i=0;i<2;i++)
#pragma unroll
      for (int r=0;r<4;r++) ok = ok && (mxv[i][r] <= mi[i][r] + 8.0f);
    if (!__all((int)ok)){
#pragma unroll
      for (int i=0;i<2;i++)
#pragma unroll
        for (int r=0;r<4;r++){
          float mnew = fmaxf(mi[i][r], mxv[i][r]);
          float alpha = __expf(mi[i][r] - mnew);
          li[i][r] *= alpha;
          mi[i][r] = mnew;
#pragma unroll
          for (int jd=0;jd<8;jd++) o[i][jd][r] *= alpha;
        }
    }
#pragma unroll
    for (int i=0;i<2;i++)
#pragma unroll
      for (int r=0;r<4;r++){
        float rs = 0.f;
#pragma unroll
        for (int j=0;j<4;j++){
          float p = __expf(s[i][j][r] - mi[i][r]);   // bounded by e^8
          s[i][j][r] = p; rs += p;
        }
        rs += __shfl_xor(rs, 1); rs += __shfl_xor(rs, 2);
        rs += __shfl_xor(rs, 4); rs += __shfl_xor(rs, 8);
        li[i][r] += rs;
      }

    // P: C-layout -> per-wave LDS strip (swizzled) -> A-layout frags
#pragma unroll
    for (int i=0;i<2;i++)
#pragma unroll
      for (int j=0;j<4;j++)
#pragma unroll
        for (int r=0;r<4;r++){
          const int rr = i*16 + lq*4 + r;
          Ps[wv*2048 + rr*64 + ((j*16 + ln) ^ ((rr & 7) << 3))] = f2b(s[i][j][r]);
        }

    bf16x8 pf[2][2];
#pragma unroll
    for (int i=0;i<2;i++){
      const int prow = i*16 + ln;
      const int psw = (prow & 7) << 3;
#pragma unroll
      for (int kc=0;kc<2;kc++)
        pf[i][kc] = ldfrag(&Ps[wv*2048 + prow*64 + ((kc*32 + lq*8) ^ psw)]);
    }
    __builtin_amdgcn_s_setprio(1);
#pragma unroll
    for (int jd=0;jd<8;jd++){
      const int vrow = jd*16 + ln;
      const int vsw = (vrow & 7) << 3;
#pragma unroll
      for (int kc=0;kc<2;kc++){
        bf16x8 vf = ldfrag(&Vt[b][vrow*64 + ((kc*32 + lq*8) ^ vsw)]);
#pragma unroll
        for (int i=0;i<2;i++)
          o[i][jd] = __builtin_amdgcn_mfma_f32_16x16x32_bf16(pf[i][kc], vf, o[i][jd], 0,0,0);
      }
    }
    __builtin_amdgcn_s_setprio(0);

    } // active
  }

  // epilogue: y over own Q tile, head-major [BH][T][HD]
#pragma unroll
  for (int i=0;i<2;i++)
#pragma unroll
    for (int r=0;r<4;r++){
      float inv = 1.f / li[i][r];
      int row = qt*128 + wv*32 + i*16 + lq*4 + r;
#pragma unroll
      for (int jd=0;jd<8;jd++)
        qy[((size_t)bh*T_ + row)*HD + jd*16 + ln] = f2b(o[i][jd][r] * inv);
    }
}

extern "C" void kernel_launch(void* const* d_in, const int* in_sizes, int n_in,
                              void* d_out, int out_size, void* d_ws, size_t ws_size,
                              hipStream_t stream)
{
  const float* x      = (const float*)d_in[0];   // [8192][2048] fp32
  const float* W_attn = (const float*)d_in[1];   // [2048][6144] fp32
  const float* b_attn = (const float*)d_in[2];   // [6144] fp32
  const float* W_proj = (const float*)d_in[3];   // [2048][2048] fp32
  const float* b_proj = (const float*)d_in[4];   // [2048] fp32
  float* out = (float*)d_out;                    // [8192][2048] fp32

  u16* Wat = (u16*)d_ws;                         // [6144][2048] bf16 = W_attn^T
  u16* Wpt = Wat + (size_t)6144*2048;            // [2048][2048] bf16 = W_proj^T
  u16* qb  = Wpt + (size_t)2048*2048;            // Q bf16, then y bf16
  u16* xb  = qb  + (size_t)BH*T_*HD;             // x bf16 (only if ws >= 96 MiB)
  u16* kb  = (u16*)d_out;                        // K bf16 (d_out low half)
  u16* vb  = kb + (size_t)BH*T_*HD;              // V bf16 (d_out high half)

  const size_t need = ((size_t)6144*2048 + (size_t)2048*2048
                       + 2*(size_t)BH*T_*HD) * sizeof(u16);   // 96 MiB
  const int big_ws = (ws_size >= need) ? 1 : 0;

  hipLaunchKernelGGL(prep, dim3(96,32,2), dim3(256,1,1), 0, stream,
                     W_attn, Wat, W_proj, Wpt,
                     (const float4*)x, (ushort4*)xb, big_ws);
  if (big_ws){
    hipLaunchKernelGGL(gemm_qkv_8p, dim3(768,1,1), dim3(512,1,1), 0, stream,
                       xb, Wat, b_attn, qb, kb, vb);
  } else {
    hipLaunchKernelGGL(gemm_qkv_f32, dim3(48,64,1), dim3(256,1,1), 0, stream,
                       x, Wat, b_attn, qb, kb, vb);
  }
  hipLaunchKernelGGL(attn_fwd, dim3(8,BH,1), dim3(256,1,1), 0, stream,
                     qb, kb, vb);
  hipLaunchKernelGGL(gemm_proj_8p, dim3(256,1,1), dim3(512,1,1), 0, stream,
                     qb, Wpt, b_proj, out);
}

// Round 8
// 569.442 us; speedup vs baseline: 1.0871x; 1.0507x over previous
//
#include <hip/hip_runtime.h>
#include <hip/hip_bf16.h>

// CausalSelfAttention: B=8 T=1024 C=2048 NH=16 HD=128. FP32 I/O, bf16 MFMA.
// R13: attn rewritten with swapped-operand QK^T (S^T = mfma(K,Q)) so each
// lane holds full P-rows in registers: in-lane softmax (2 shuffles vs 8/row),
// NO Ps LDS buffer (PV B-frag = in-lane pk2 packs under k-permutation
// pi(lq,e) applied to both PV operands; V A-frag = 2x8B reads from swizzled
// Vt), packed 8B epilogue stores. GEMMs/staging/dbuf frozen at R12 state.
// ws: Wat^T 24M | Wpt^T 8M | Q 32M (y overwrites Q after attn) | [xb 32M].
// d_out: K bf16 | V bf16 until proj GEMM overwrites with fp32 result.

typedef unsigned short u16;
typedef unsigned int u32;
typedef __bf16 bf16x8 __attribute__((ext_vector_type(8)));
typedef float f32x4 __attribute__((ext_vector_type(4)));

#define B_ 8
#define T_ 1024
#define C_ 2048
#define NH 16
#define HD 128
#define BH (B_*NH)

__device__ __forceinline__ u16 f2b(float f){
  __bf16 h = (__bf16)f; return __builtin_bit_cast(u16, h);   // RNE
}
__device__ __forceinline__ unsigned pk2(float x, float y){
  return (unsigned)f2b(x) | ((unsigned)f2b(y) << 16);
}
__device__ __forceinline__ bf16x8 ldfrag(const u16* p){
  uint4 u = *(const uint4*)p; return __builtin_bit_cast(bf16x8, u);
}
__device__ __forceinline__ void glds16(const u16* g, const u16* l){
  __builtin_amdgcn_global_load_lds(
      (const __attribute__((address_space(1))) void*)g,
      (__attribute__((address_space(3))) void*)l, 16, 0, 0);
}
__device__ __forceinline__ void sbar(){
  __builtin_amdgcn_sched_barrier(0);
  __builtin_amdgcn_s_barrier();
  __builtin_amdgcn_sched_barrier(0);
}

// ---------------- fused pre-pass: W transposes + x cvt ----------------------
__global__ __launch_bounds__(256) void prep(
    const float* __restrict__ W_attn, u16* __restrict__ Wat,
    const float* __restrict__ W_proj, u16* __restrict__ Wpt,
    const float4* __restrict__ x4, ushort4* __restrict__ xb4, int do_cvt)
{
  __shared__ u16 tile[64][65];
  const int t = threadIdx.x;
  const int z = blockIdx.z;
  if (z == 1 && blockIdx.x >= 32){
    if (!do_cvt) return;
    const int n4 = (B_*T_*C_)/4;
    int i = ((blockIdx.x - 32)*32 + blockIdx.y)*256 + t;
    const int stride = 2048*256;
    for (; i < n4; i += stride){
      float4 f = x4[i];
      ushort4 o; o.x = f2b(f.x); o.y = f2b(f.y); o.z = f2b(f.z); o.w = f2b(f.w);
      xb4[i] = o;
    }
    return;
  }
  const float* in = (z == 0) ? W_attn : W_proj;
  u16* outp       = (z == 0) ? Wat    : Wpt;
  const int R = 2048, C = (z == 0) ? 6144 : 2048;
  const int r0 = blockIdx.y * 64, c0 = blockIdx.x * 64;
#pragma unroll
  for (int ii = 0; ii < 16; ++ii){
    int idx = t + ii*256; int r = idx >> 6, c = idx & 63;
    tile[r][c] = f2b(in[(size_t)(r0 + r)*C + c0 + c]);
  }
  __syncthreads();
#pragma unroll
  for (int ii = 0; ii < 16; ++ii){
    int idx = t + ii*256; int r = idx >> 6, c = idx & 63;
    outp[(size_t)(c0 + r)*R + r0 + c] = tile[c][r];
  }
}

// ---------------- QKV epilogue for 128-tile fallback path -------------------
__device__ __forceinline__ void qkv_epilogue(
    const f32x4 acc[4][4], const float* bias, int bx, int by,
    int wm, int wn, int lq, int ln,
    u16* qb, u16* kb, u16* vb)
{
  const int tensor = bx >> 4, h = bx & 15, b = by >> 3, t0 = (by & 7)*128;
  u16* tb = tensor==0 ? qb : (tensor==1 ? kb : vb);
  u16* op = tb + ((size_t)(b*NH + h)*T_ + t0)*HD;
#pragma unroll
  for (int j=0;j<4;j++){
    const float bv = bias[bx*128 + wn*64 + j*16 + ln];
    const int n = wn*64 + j*16 + ln;
#pragma unroll
    for (int i=0;i<4;i++){
      const int m0 = wm*64 + i*16 + lq*4;      // C/D: row = quad*4 + reg
#pragma unroll
      for (int r=0;r<4;r++)
        op[(size_t)(m0 + r)*HD + n] = f2b(acc[i][j][r] + bv);
    }
  }
}

// ---------------- QKV GEMM, 256x256 8-phase (R10-proven schedule) -----------
__global__ __launch_bounds__(512,2) void gemm_qkv_8p(
    const u16* __restrict__ Xb, const u16* __restrict__ Wt,
    const float* __restrict__ bias,
    u16* __restrict__ qb, u16* __restrict__ kb, u16* __restrict__ vb)
{
  __shared__ u16 lds[2][2][256*64];            // [buf][A/B][row][k] 128 KiB
  const int t = threadIdx.x;                   // 0..511
  const int lane = t & 63, wid = t >> 6;       // 8 waves: 2M x 4N
  const int lq = lane >> 4, ln = lane & 15;
  const int wm = wid >> 2, wn = wid & 3;

  // XCD-aware swizzle (768 blocks, 768%8==0 -> simple form is bijective)
  const int bid0 = blockIdx.x;
  const int bid = (bid0 & 7)*96 + (bid0 >> 3);
  const int bx = bid % 24, by = bid / 24;      // bx: N/256, by: M/256

  const int rl  = (wid << 4) + (lane >> 3);    // q=0 local row (0..127)
  const int sw0 = (lane & 7) ^ (rl & 7);
  const u16* Ag = Xb + ((size_t)(by*256) + rl)*2048;
  const u16* Bg = Wt + ((size_t)(bx*256) + rl)*2048;
  const size_t q0off = (size_t)sw0*8;
  const size_t q1off = (size_t)8*2048 + (size_t)sw0*8;   // (rl+8)&7 == rl&7

#define STAGE(buf_, op_, h_, T_) do { \
    const u16* s_ = (op_ ? Bg : Ag) + (size_t)(h_)*(128*2048) + (size_t)(T_)*64; \
    const u16* d_ = &lds[buf_][op_][(((h_)*128) + (wid<<4))*64]; \
    glds16(s_ + q0off, d_); \
    glds16(s_ + q1off, d_ + 8*64); \
  } while(0)

  const int swr0 = (0*4 + lq) ^ (ln & 7);
  const int swr1 = (1*4 + lq) ^ (ln & 7);

  const f32x4 fz = {0.f,0.f,0.f,0.f};
  f32x4 acc[8][4];
#pragma unroll
  for (int f=0;f<8;f++)
#pragma unroll
    for (int g=0;g<4;g++) acc[f][g] = fz;

  // prologue: tile0 fully + tile1's Bhi,Blo,Ahi (Alo(1) comes at (0,+0))
  STAGE(0,0,0,0); STAGE(0,0,1,0); STAGE(0,1,0,0); STAGE(0,1,1,0);
  STAGE(1,1,0,1); STAGE(1,1,1,1); STAGE(1,0,0,1);
  asm volatile("s_waitcnt vmcnt(6)" ::: "memory");   // tile0 landed
  sbar();

  for (int T = 0; T < 32; ++T){
    const int b = T & 1;
    const u16* As = lds[b][0];
    const u16* Bs = lds[b][1];
    bf16x8 a0[4][2], a4[4][2], bfr[4][2];

    // ---- phase +0: read A frags 0-3 + all B frags; stage Alo(T+1)
#pragma unroll
    for (int f=0;f<4;f++){
      a0[f][0]  = ldfrag(&As[(wm*128 + f*16 + ln)*64 + swr0*8]);
      a0[f][1]  = ldfrag(&As[(wm*128 + f*16 + ln)*64 + swr1*8]);
      bfr[f][0] = ldfrag(&Bs[(wn*64  + f*16 + ln)*64 + swr0*8]);
      bfr[f][1] = ldfrag(&Bs[(wn*64  + f*16 + ln)*64 + swr1*8]);
    }
    if (T+1 < 32) STAGE(b^1, 0, 1, T+1);
    sbar();
    __builtin_amdgcn_s_setprio(1);
#pragma unroll
    for (int f=0;f<4;f++)
#pragma unroll
      for (int g=0;g<2;g++){
        acc[f][g] = __builtin_amdgcn_mfma_f32_16x16x32_bf16(a0[f][0], bfr[g][0], acc[f][g], 0,0,0);
        acc[f][g] = __builtin_amdgcn_mfma_f32_16x16x32_bf16(a0[f][1], bfr[g][1], acc[f][g], 0,0,0);
      }
    __builtin_amdgcn_s_setprio(0);
    sbar();

    // ---- phase +1: read A frags 4-7; stage Bhi(T+2)
#pragma unroll
    for (int f=0;f<4;f++){
      a4[f][0] = ldfrag(&As[(wm*128 + (f+4)*16 + ln)*64 + swr0*8]);
      a4[f][1] = ldfrag(&As[(wm*128 + (f+4)*16 + ln)*64 + swr1*8]);
    }
    if (T+2 < 32) STAGE(b, 1, 0, T+2);
    sbar();
    __builtin_amdgcn_s_setprio(1);
#pragma unroll
    for (int f=0;f<4;f++)
#pragma unroll
      for (int g=0;g<2;g++){
        acc[f+4][g] = __builtin_amdgcn_mfma_f32_16x16x32_bf16(a4[f][0], bfr[g][0], acc[f+4][g], 0,0,0);
        acc[f+4][g] = __builtin_amdgcn_mfma_f32_16x16x32_bf16(a4[f][1], bfr[g][1], acc[f+4][g], 0,0,0);
      }
    __builtin_amdgcn_s_setprio(0);
    sbar();

    // ---- phase +2: no reads; stage Blo(T+2)
    if (T+2 < 32) STAGE(b, 1, 1, T+2);
    sbar();
    __builtin_amdgcn_s_setprio(1);
#pragma unroll
    for (int f=0;f<4;f++)
#pragma unroll
      for (int g=2;g<4;g++){
        acc[f+4][g] = __builtin_amdgcn_mfma_f32_16x16x32_bf16(a4[f][0], bfr[g][0], acc[f+4][g], 0,0,0);
        acc[f+4][g] = __builtin_amdgcn_mfma_f32_16x16x32_bf16(a4[f][1], bfr[g][1], acc[f+4][g], 0,0,0);
      }
    __builtin_amdgcn_s_setprio(0);
    sbar();

    // ---- phase +3: no reads; stage Ahi(T+2); counted vmcnt
    if (T+2 < 32) STAGE(b, 0, 0, T+2);
    if (T >= 30) asm volatile("s_waitcnt vmcnt(0)" ::: "memory");
    else         asm volatile("s_waitcnt vmcnt(6)" ::: "memory");
    sbar();
    __builtin_amdgcn_s_setprio(1);
#pragma unroll
    for (int f=0;f<4;f++)
#pragma unroll
      for (int g=2;g<4;g++){
        acc[f][g] = __builtin_amdgcn_mfma_f32_16x16x32_bf16(a0[f][0], bfr[g][0], acc[f][g], 0,0,0);
        acc[f][g] = __builtin_amdgcn_mfma_f32_16x16x32_bf16(a0[f][1], bfr[g][1], acc[f][g], 0,0,0);
      }
    __builtin_amdgcn_s_setprio(0);
    sbar();
  }
#undef STAGE

  // epilogue: scatter to Q/K/V [BH][T][HD]
  const int tensor = bx >> 3;
  u16* tb = tensor==0 ? qb : (tensor==1 ? kb : vb);
  const int m_base = by*256 + wm*128;
#pragma unroll
  for (int g=0; g<4; ++g){
    const int ncol = (bx & 7)*256 + wn*64 + g*16 + ln;   // 0..2047 in tensor
    const float bv = bias[tensor*2048 + ncol];
    const int h = ncol >> 7, d = ncol & 127;
#pragma unroll
    for (int f=0; f<8; ++f){
      const int m0 = m_base + f*16 + lq*4;
      const int bb = m0 >> 10, tt = m0 & 1023;           // rows m0..m0+3 same b
      u16* op = tb + ((size_t)(bb*NH + h)*T_ + tt)*HD + d;
#pragma unroll
      for (int r=0;r<4;++r)
        op[(size_t)r*HD] = f2b(acc[f][g][r] + bv);
    }
  }
}

// ---------------- proj GEMM, 256x256 8-phase (R10-proven schedule) ----------
__global__ __launch_bounds__(512,2) void gemm_proj_8p(
    const u16* __restrict__ Y, const u16* __restrict__ Wt,
    const float* __restrict__ bias, float* __restrict__ outp)
{
  __shared__ u16 lds[2][2][256*64];            // [buf][A/B][row][k] 128 KiB
  const int t = threadIdx.x;
  const int lane = t & 63, wid = t >> 6;
  const int lq = lane >> 4, ln = lane & 15;
  const int wm = wid >> 2, wn = wid & 3;

  // 256 blocks, 256%8==0 -> bijective XCD swizzle
  const int bid0 = blockIdx.x;
  const int bid = (bid0 & 7)*32 + (bid0 >> 3);
  const int bx = bid & 7, by = bid >> 3;       // bx: N/256 (8), by: M/256 (32)

  const int rl  = (wid << 4) + (lane >> 3);
  const int sw0 = (lane & 7) ^ (rl & 7);
  const u16* Bg = Wt + ((size_t)(bx*256) + rl)*2048;
  const size_t bq0 = (size_t)sw0*8;
  const size_t arow0 = ((size_t)(by >> 2)*16)*1024 + (size_t)(by & 3)*256 + rl;

#define STAGEP(buf_, op_, h_, Tt_) do { \
    const u16* d_ = &lds[buf_][op_][(((h_)*128) + (wid<<4))*64]; \
    if (op_){ \
      const u16* s_ = Bg + (size_t)(h_)*(128*2048) + (size_t)(Tt_)*64; \
      glds16(s_ + bq0, d_); \
      glds16(s_ + (size_t)8*2048 + bq0, d_ + 8*64); \
    } else { \
      const u16* s_ = Y + (arow0 + (size_t)((Tt_) >> 1)*1024 + (size_t)(h_)*128)*128 \
                        + ((Tt_) & 1)*64 + sw0*8; \
      glds16(s_, d_); \
      glds16(s_ + 8*128, d_ + 8*64); \
    } \
  } while(0)

  const int swr0 = (0*4 + lq) ^ (ln & 7);
  const int swr1 = (1*4 + lq) ^ (ln & 7);

  const f32x4 fz = {0.f,0.f,0.f,0.f};
  f32x4 acc[8][4];
#pragma unroll
  for (int f=0;f<8;f++)
#pragma unroll
    for (int g=0;g<4;g++) acc[f][g] = fz;

  STAGEP(0,0,0,0); STAGEP(0,0,1,0); STAGEP(0,1,0,0); STAGEP(0,1,1,0);
  STAGEP(1,1,0,1); STAGEP(1,1,1,1); STAGEP(1,0,0,1);
  asm volatile("s_waitcnt vmcnt(6)" ::: "memory");
  sbar();

  for (int T = 0; T < 32; ++T){
    const int b = T & 1;
    const u16* As = lds[b][0];
    const u16* Bs = lds[b][1];
    bf16x8 a0[4][2], a4[4][2], bfr[4][2];

#pragma unroll
    for (int f=0;f<4;f++){
      a0[f][0]  = ldfrag(&As[(wm*128 + f*16 + ln)*64 + swr0*8]);
      a0[f][1]  = ldfrag(&As[(wm*128 + f*16 + ln)*64 + swr1*8]);
      bfr[f][0] = ldfrag(&Bs[(wn*64  + f*16 + ln)*64 + swr0*8]);
      bfr[f][1] = ldfrag(&Bs[(wn*64  + f*16 + ln)*64 + swr1*8]);
    }
    if (T+1 < 32) STAGEP(b^1, 0, 1, T+1);
    sbar();
    __builtin_amdgcn_s_setprio(1);
#pragma unroll
    for (int f=0;f<4;f++)
#pragma unroll
      for (int g=0;g<2;g++){
        acc[f][g] = __builtin_amdgcn_mfma_f32_16x16x32_bf16(a0[f][0], bfr[g][0], acc[f][g], 0,0,0);
        acc[f][g] = __builtin_amdgcn_mfma_f32_16x16x32_bf16(a0[f][1], bfr[g][1], acc[f][g], 0,0,0);
      }
    __builtin_amdgcn_s_setprio(0);
    sbar();

#pragma unroll
    for (int f=0;f<4;f++){
      a4[f][0] = ldfrag(&As[(wm*128 + (f+4)*16 + ln)*64 + swr0*8]);
      a4[f][1] = ldfrag(&As[(wm*128 + (f+4)*16 + ln)*64 + swr1*8]);
    }
    if (T+2 < 32) STAGEP(b, 1, 0, T+2);
    sbar();
    __builtin_amdgcn_s_setprio(1);
#pragma unroll
    for (int f=0;f<4;f++)
#pragma unroll
      for (int g=0;g<2;g++){
        acc[f+4][g] = __builtin_amdgcn_mfma_f32_16x16x32_bf16(a4[f][0], bfr[g][0], acc[f+4][g], 0,0,0);
        acc[f+4][g] = __builtin_amdgcn_mfma_f32_16x16x32_bf16(a4[f][1], bfr[g][1], acc[f+4][g], 0,0,0);
      }
    __builtin_amdgcn_s_setprio(0);
    sbar();

    if (T+2 < 32) STAGEP(b, 1, 1, T+2);
    sbar();
    __builtin_amdgcn_s_setprio(1);
#pragma unroll
    for (int f=0;f<4;f++)
#pragma unroll
      for (int g=2;g<4;g++){
        acc[f+4][g] = __builtin_amdgcn_mfma_f32_16x16x32_bf16(a4[f][0], bfr[g][0], acc[f+4][g], 0,0,0);
        acc[f+4][g] = __builtin_amdgcn_mfma_f32_16x16x32_bf16(a4[f][1], bfr[g][1], acc[f+4][g], 0,0,0);
      }
    __builtin_amdgcn_s_setprio(0);
    sbar();

    if (T+2 < 32) STAGEP(b, 0, 0, T+2);
    if (T >= 30) asm volatile("s_waitcnt vmcnt(0)" ::: "memory");
    else         asm volatile("s_waitcnt vmcnt(6)" ::: "memory");
    sbar();
    __builtin_amdgcn_s_setprio(1);
#pragma unroll
    for (int f=0;f<4;f++)
#pragma unroll
      for (int g=2;g<4;g++){
        acc[f][g] = __builtin_amdgcn_mfma_f32_16x16x32_bf16(a0[f][0], bfr[g][0], acc[f][g], 0,0,0);
        acc[f][g] = __builtin_amdgcn_mfma_f32_16x16x32_bf16(a0[f][1], bfr[g][1], acc[f][g], 0,0,0);
      }
    __builtin_amdgcn_s_setprio(0);
    sbar();
  }
#undef STAGEP

  // epilogue: fp32 out [8192][2048]
  const int m_base = by*256 + wm*128;
#pragma unroll
  for (int g=0; g<4; ++g){
    const int ncol = bx*256 + wn*64 + g*16 + ln;
    const float bv = bias[ncol];
#pragma unroll
    for (int f=0; f<8; ++f){
      const int m0 = m_base + f*16 + lq*4;
      float* op = outp + (size_t)m0*2048 + ncol;
#pragma unroll
      for (int r=0;r<4;++r)
        op[(size_t)r*2048] = acc[f][g][r] + bv;
    }
  }
}

// ---------------- QKV GEMM, fallback: A = x fp32 (cvt in staging). ----------
__global__ __launch_bounds__(256,2) void gemm_qkv_f32(
    const float* __restrict__ X, const u16* __restrict__ Wt, const float* __restrict__ bias,
    u16* __restrict__ qb, u16* __restrict__ kb, u16* __restrict__ vb)
{
  __shared__ u16 As[128*32];
  __shared__ u16 Bs[128*32];
  const int t = threadIdx.x;
  const int bx = blockIdx.x, by = blockIdx.y;
  const int lane = t & 63, wv = t >> 6;
  const int lq = lane >> 4, ln = lane & 15;
  const int wm = wv >> 1, wn = wv & 1;

  const int ar = t >> 1, ah = t & 1;
  const float* Ap = X + (size_t)(by*128 + ar)*2048 + ah*16;
  u16* AsW = &As[ar*32 + ah*16];

  const int c0 = t, c1 = 256 + t;
  const u16* Bp0 = Wt + (size_t)(bx*128 + (c0 >> 2))*2048 + (c0 & 3)*8;
  const u16* Bp1 = Wt + (size_t)(bx*128 + (c1 >> 2))*2048 + (c1 & 3)*8;
  const u16* BsW0 = &Bs[(wv*64)*8];
  const u16* BsW1 = &Bs[(256 + wv*64)*8];

  const f32x4 fz = {0.f,0.f,0.f,0.f};
  f32x4 acc[4][4];
#pragma unroll
  for (int i=0;i<4;i++)
#pragma unroll
    for (int j=0;j<4;j++) acc[i][j] = fz;

  for (int kt = 0; kt < 64; ++kt){
    float4 a0 = *(const float4*)(Ap);
    float4 a1 = *(const float4*)(Ap + 4);
    float4 a2 = *(const float4*)(Ap + 8);
    float4 a3 = *(const float4*)(Ap + 12);
    Ap += 32;
    __syncthreads();
    uint4 w0, w1;
    w0.x = pk2(a0.x,a0.y); w0.y = pk2(a0.z,a0.w);
    w0.z = pk2(a1.x,a1.y); w0.w = pk2(a1.z,a1.w);
    w1.x = pk2(a2.x,a2.y); w1.y = pk2(a2.z,a2.w);
    w1.z = pk2(a3.x,a3.y); w1.w = pk2(a3.z,a3.w);
    *(uint4*)(AsW) = w0; *(uint4*)(AsW + 8) = w1;
    glds16(Bp0, BsW0);
    glds16(Bp1, BsW1);
    Bp0 += 32; Bp1 += 32;
    __syncthreads();
    bf16x8 af[4], bf[4];
#pragma unroll
    for (int i=0;i<4;i++) af[i] = ldfrag(&As[(wm*64 + i*16 + ln)*32 + lq*8]);
#pragma unroll
    for (int j=0;j<4;j++) bf[j] = ldfrag(&Bs[(wn*64 + j*16 + ln)*32 + lq*8]);
#pragma unroll
    for (int i=0;i<4;i++)
#pragma unroll
      for (int j=0;j<4;j++)
        acc[i][j] = __builtin_amdgcn_mfma_f32_16x16x32_bf16(af[i], bf[j], acc[i][j], 0,0,0);
  }
  qkv_epilogue(acc, bias, bx, by, wm, wn, lq, ln, qb, kb, vb);
}

// ---------------- flash attention, R13: swapped-operand in-register softmax -
// S^T = mfma(K,Q): lane(lq,ln) holds S[q=i*16+ln][key=j*16+lq*4+r] in s[i][j][r].
// Softmax per q-row: in-lane 16-val tree + shfl_xor(16,32). PV via k-slot
// permutation pi(lq,e): chunk c keys = {c*16+4lq+0..3, (c+2)*16+4lq+0..3};
// B-frag = in-lane pk2 of s (no LDS); A-frag = 2x8B reads of swizzled Vt.
// O^T accum: o[i][jd][r] = O[q=i*16+ln][d=jd*16+lq*4+r]; packed 8B stores.
__global__ __launch_bounds__(256,2) void attn_fwd(
    u16* qy, const u16* __restrict__ kk, const u16* __restrict__ vv)
{
  __shared__ u16 Ks[2][64*128];                // [buf][key][d], swizzled
  __shared__ u16 Vt[2][128*64];                // [buf][d][key], swizzled
  const int qt = 7 - blockIdx.x, bh = blockIdx.y;
  const int t = threadIdx.x;
  const int lane = t & 63, wv = t >> 6;
  const int lq = lane >> 4, ln = lane & 15;

  bf16x8 qf[2][4];                             // per-lane: Q[i*16+ln][kc*32+lq*8..]
#pragma unroll
  for (int i=0;i<2;i++)
#pragma unroll
    for (int kc=0;kc<4;kc++){
      int qrow = qt*128 + wv*32 + i*16 + ln;
      qf[i][kc] = ldfrag(&qy[((size_t)bh*T_ + qrow)*HD + kc*32 + lq*8]);
    }

  const f32x4 fz = {0.f,0.f,0.f,0.f};
  f32x4 o[2][8];                               // O^T frags
#pragma unroll
  for (int i=0;i<2;i++)
#pragma unroll
    for (int jd=0;jd<8;jd++) o[i][jd] = fz;
  float mi[2] = {-1e30f, -1e30f}, li[2] = {0.f, 0.f};

  const float scale = 0.08838834764831843f;    // 1/sqrt(128)
  const int kr = t & 63, dbase = (t >> 6)*32;  // V-transpose stage mapping
  const int nkt = 2*qt + 2;                    // causal: keys < (qt+1)*128

  uint4 kreg[4];
  uint4 vreg[4];
  {
    const uint4* ksrc = (const uint4*)(kk + (size_t)bh*T_*HD);
#pragma unroll
    for (int ii=0; ii<4; ++ii) kreg[ii] = ksrc[t + ii*256];
#pragma unroll
    for (int ch=0; ch<4; ++ch)
      vreg[ch] = *(const uint4*)&vv[((size_t)bh*T_ + kr)*HD + dbase + ch*8];
  }

  for (int kt = 0; kt < nkt; ++kt){
    const int b = kt & 1;
    uint4* kdst = (uint4*)Ks[b];
#pragma unroll
    for (int ii=0; ii<4; ++ii){
      const int c = t + ii*256;                // chunk: row c>>4, slot c&15
      kdst[(c & ~15) | ((c & 15) ^ ((c >> 4) & 7))] = kreg[ii];
    }
#pragma unroll
    for (int ch=0; ch<4; ++ch){
      const u16* e = (const u16*)&vreg[ch];
#pragma unroll
      for (int j=0; j<8; ++j){
        const int d = dbase + ch*8 + j;
        Vt[b][d*64 + (kr ^ ((d & 7) << 3))] = e[j]; // distinct cols/lane: free
      }
    }
    {
      const int ktn = (kt+1 < nkt) ? kt+1 : kt;   // last iter: harmless reload
      const uint4* ksrc = (const uint4*)(kk + ((size_t)bh*T_ + ktn*64)*HD);
#pragma unroll
      for (int ii=0; ii<4; ++ii) kreg[ii] = ksrc[t + ii*256];
#pragma unroll
      for (int ch=0; ch<4; ++ch)
        vreg[ch] = *(const uint4*)&vv[((size_t)bh*T_ + ktn*64 + kr)*HD + dbase + ch*8];
    }
    __syncthreads();                           // buffer b fully written

    const bool active = (kt*64) <= (qt*128 + wv*32 + 31);
    if (active){

    // S^T = K Q^T (operand-swapped: A=K frag, B=Q frag; same reg layouts)
    f32x4 s[2][4];
#pragma unroll
    for (int i=0;i<2;i++)
#pragma unroll
      for (int j=0;j<4;j++) s[i][j] = fz;
    __builtin_amdgcn_s_setprio(1);
#pragma unroll
    for (int j=0;j<4;j++){
      bf16x8 kf[4];
      const int krow = j*16 + ln;
      const int ksw = (krow & 7) << 3;
#pragma unroll
      for (int kc=0;kc<4;kc++)
        kf[kc] = ldfrag(&Ks[b][krow*128 + ((kc*32 + lq*8) ^ ksw)]);
#pragma unroll
      for (int i=0;i<2;i++)
#pragma unroll
        for (int kc=0;kc<4;kc++)
          s[i][j] = __builtin_amdgcn_mfma_f32_16x16x32_bf16(kf[kc], qf[i][kc], s[i][j], 0,0,0);
    }
    __builtin_amdgcn_s_setprio(0);

    // scale + causal mask: q = ..+i*16+ln (col), key = kt*64+j*16+lq*4+r (row)
#pragma unroll
    for (int i=0;i<2;i++){
      const int qg = qt*128 + wv*32 + i*16 + ln;
#pragma unroll
      for (int j=0;j<4;j++)
#pragma unroll
        for (int r=0;r<4;r++){
          const int kg = kt*64 + j*16 + lq*4 + r;
          float sv = s[i][j][r]*scale;
          s[i][j][r] = (kg > qg) ? -1e30f : sv;
        }
    }

    // in-register softmax per q-row (16 vals/lane + 2 shuffles), defer-max THR=8
    float mx[2];
#pragma unroll
    for (int i=0;i<2;i++){
      float m = s[i][0][0];
#pragma unroll
      for (int j=0;j<4;j++)
#pragma unroll
        for (int r=0;r<4;r++) m = fmaxf(m, s[i][j][r]);
      m = fmaxf(m, __shfl_xor(m, 16));
      m = fmaxf(m, __shfl_xor(m, 32));
      mx[i] = m;
    }
    bool ok = (mx[0] <= mi[0] + 8.0f) && (mx[1] <= mi[1] + 8.0f);
    if (!__all((int)ok)){
#pragma unroll
      for (int i=0;i<2;i++){
        float mnew = fmaxf(mi[i], mx[i]);
        float alpha = __expf(mi[i] - mnew);
        li[i] *= alpha;
        mi[i] = mnew;
#pragma unroll
        for (int jd=0;jd<8;jd++)
#pragma unroll
          for (int r=0;r<4;r++) o[i][jd][r] *= alpha;
      }
    }
#pragma unroll
    for (int i=0;i<2;i++){
      float rs = 0.f;
#pragma unroll
      for (int j=0;j<4;j++)
#pragma unroll
        for (int r=0;r<4;r++){
          float p = __expf(s[i][j][r] - mi[i]);   // bounded by e^8
          s[i][j][r] = p; rs += p;
        }
      rs += __shfl_xor(rs, 16);
      rs += __shfl_xor(rs, 32);
      li[i] += rs;
    }

    // PV: O^T += V^T P^T under k-permutation pi(lq,e).
    // B-frag (P^T) chunk c: in-lane pack, keys {c*16+4lq+r, (c+2)*16+4lq+r}.
    bf16x8 pb[2][2];
#pragma unroll
    for (int i=0;i<2;i++)
#pragma unroll
      for (int c=0;c<2;c++){
        uint4 w;
        w.x = pk2(s[i][c][0],   s[i][c][1]);
        w.y = pk2(s[i][c][2],   s[i][c][3]);
        w.z = pk2(s[i][c+2][0], s[i][c+2][1]);
        w.w = pk2(s[i][c+2][2], s[i][c+2][3]);
        pb[i][c] = __builtin_bit_cast(bf16x8, w);
      }
    __builtin_amdgcn_s_setprio(1);
#pragma unroll
    for (int jd=0;jd<8;jd++){
      const int vrow = jd*16 + ln;
      const int vsw = (vrow & 7) << 3;
#pragma unroll
      for (int c=0;c<2;c++){
        // A-frag (V^T): elems 0-3 keys c*16+4lq.., elems 4-7 keys (c+2)*16+4lq..
        uint2 vlo = *(const uint2*)&Vt[b][vrow*64 + ((c*16     + lq*4) ^ vsw)];
        uint2 vhi = *(const uint2*)&Vt[b][vrow*64 + (((c+2)*16 + lq*4) ^ vsw)];
        uint4 vw; vw.x = vlo.x; vw.y = vlo.y; vw.z = vhi.x; vw.w = vhi.y;
        const bf16x8 va = __builtin_bit_cast(bf16x8, vw);
#pragma unroll
        for (int i=0;i<2;i++)
          o[i][jd] = __builtin_amdgcn_mfma_f32_16x16x32_bf16(va, pb[i][c], o[i][jd], 0,0,0);
      }
    }
    __builtin_amdgcn_s_setprio(0);

    } // active
  }

  // epilogue: packed 8B stores; lane holds q=..+i*16+ln, d=jd*16+lq*4+r
#pragma unroll
  for (int i=0;i<2;i++){
    const float inv = 1.f / li[i];
    const int q = qt*128 + wv*32 + i*16 + ln;
#pragma unroll
    for (int jd=0;jd<8;jd++){
      ushort4 w;
      w.x = f2b(o[i][jd][0] * inv);
      w.y = f2b(o[i][jd][1] * inv);
      w.z = f2b(o[i][jd][2] * inv);
      w.w = f2b(o[i][jd][3] * inv);
      *(ushort4*)&qy[((size_t)bh*T_ + q)*HD + jd*16 + lq*4] = w;
    }
  }
}

extern "C" void kernel_launch(void* const* d_in, const int* in_sizes, int n_in,
                              void* d_out, int out_size, void* d_ws, size_t ws_size,
                              hipStream_t stream)
{
  const float* x      = (const float*)d_in[0];   // [8192][2048] fp32
  const float* W_attn = (const float*)d_in[1];   // [2048][6144] fp32
  const float* b_attn = (const float*)d_in[2];   // [6144] fp32
  const float* W_proj = (const float*)d_in[3];   // [2048][2048] fp32
  const float* b_proj = (const float*)d_in[4];   // [2048] fp32
  float* out = (float*)d_out;                    // [8192][2048] fp32

  u16* Wat = (u16*)d_ws;                         // [6144][2048] bf16 = W_attn^T
  u16* Wpt = Wat + (size_t)6144*2048;            // [2048][2048] bf16 = W_proj^T
  u16* qb  = Wpt + (size_t)2048*2048;            // Q bf16, then y bf16
  u16* xb  = qb  + (size_t)BH*T_*HD;             // x bf16 (only if ws >= 96 MiB)
  u16* kb  = (u16*)d_out;                        // K bf16 (d_out low half)
  u16* vb  = kb + (size_t)BH*T_*HD;              // V bf16 (d_out high half)

  const size_t need = ((size_t)6144*2048 + (size_t)2048*2048
                       + 2*(size_t)BH*T_*HD) * sizeof(u16);   // 96 MiB
  const int big_ws = (ws_size >= need) ? 1 : 0;

  hipLaunchKernelGGL(prep, dim3(96,32,2), dim3(256,1,1), 0, stream,
                     W_attn, Wat, W_proj, Wpt,
                     (const float4*)x, (ushort4*)xb, big_ws);
  if (big_ws){
    hipLaunchKernelGGL(gemm_qkv_8p, dim3(768,1,1), dim3(512,1,1), 0, stream,
                       xb, Wat, b_attn, qb, kb, vb);
  } else {
    hipLaunchKernelGGL(gemm_qkv_f32, dim3(48,64,1), dim3(256,1,1), 0, stream,
                       x, Wat, b_attn, qb, kb, vb);
  }
  hipLaunchKernelGGL(attn_fwd, dim3(8,BH,1), dim3(256,1,1), 0, stream,
                     qb, kb, vb);
  hipLaunchKernelGGL(gemm_proj_8p, dim3(256,1,1), dim3(512,1,1), 0, stream,
                     qb, Wpt, b_proj, out);
}

// Round 9
// 520.326 us; speedup vs baseline: 1.1897x; 1.0944x over previous
//
#include <hip/hip_runtime.h>
#include <hip/hip_bf16.h>

// CausalSelfAttention: B=8 T=1024 C=2048 NH=16 HD=128. FP32 I/O, bf16 MFMA.
// R14: attn-only changes. (a) grid swapped to (BH,8) so the 8 blocks sharing
// one bh's K/V land on the SAME XCD (id%8 = bh%8) -> K/V L2-resident (~8
// resident bh x 512KB = 4MB = one XCD L2); heavy-first via qt=7-blockIdx.y.
// (b) V-stage writes packed: thread owns key pair (2p,2p+1) -> 16x
// ds_write_b32 instead of 32x ds_write_b16 (slot = 2p^((d&7)<<3), XOR in
// bits 3-5 keeps pairs aligned; 2 lanes/bank = free). GEMMs frozen at R10
// schedule (R11 rebalance regressed; R12/R13 reproduced 219-222us).
// ws: Wat^T 24M | Wpt^T 8M | Q 32M (y overwrites Q after attn) | [xb 32M].
// d_out: K bf16 | V bf16 until proj GEMM overwrites with fp32 result.

typedef unsigned short u16;
typedef unsigned int u32;
typedef __bf16 bf16x8 __attribute__((ext_vector_type(8)));
typedef float f32x4 __attribute__((ext_vector_type(4)));

#define B_ 8
#define T_ 1024
#define C_ 2048
#define NH 16
#define HD 128
#define BH (B_*NH)

__device__ __forceinline__ u16 f2b(float f){
  __bf16 h = (__bf16)f; return __builtin_bit_cast(u16, h);   // RNE
}
__device__ __forceinline__ unsigned pk2(float x, float y){
  return (unsigned)f2b(x) | ((unsigned)f2b(y) << 16);
}
__device__ __forceinline__ bf16x8 ldfrag(const u16* p){
  uint4 u = *(const uint4*)p; return __builtin_bit_cast(bf16x8, u);
}
__device__ __forceinline__ void glds16(const u16* g, const u16* l){
  __builtin_amdgcn_global_load_lds(
      (const __attribute__((address_space(1))) void*)g,
      (__attribute__((address_space(3))) void*)l, 16, 0, 0);
}
__device__ __forceinline__ void sbar(){
  __builtin_amdgcn_sched_barrier(0);
  __builtin_amdgcn_s_barrier();
  __builtin_amdgcn_sched_barrier(0);
}

// ---------------- fused pre-pass: W transposes + x cvt ----------------------
__global__ __launch_bounds__(256) void prep(
    const float* __restrict__ W_attn, u16* __restrict__ Wat,
    const float* __restrict__ W_proj, u16* __restrict__ Wpt,
    const float4* __restrict__ x4, ushort4* __restrict__ xb4, int do_cvt)
{
  __shared__ u16 tile[64][65];
  const int t = threadIdx.x;
  const int z = blockIdx.z;
  if (z == 1 && blockIdx.x >= 32){
    if (!do_cvt) return;
    const int n4 = (B_*T_*C_)/4;
    int i = ((blockIdx.x - 32)*32 + blockIdx.y)*256 + t;
    const int stride = 2048*256;
    for (; i < n4; i += stride){
      float4 f = x4[i];
      ushort4 o; o.x = f2b(f.x); o.y = f2b(f.y); o.z = f2b(f.z); o.w = f2b(f.w);
      xb4[i] = o;
    }
    return;
  }
  const float* in = (z == 0) ? W_attn : W_proj;
  u16* outp       = (z == 0) ? Wat    : Wpt;
  const int R = 2048, C = (z == 0) ? 6144 : 2048;
  const int r0 = blockIdx.y * 64, c0 = blockIdx.x * 64;
#pragma unroll
  for (int ii = 0; ii < 16; ++ii){
    int idx = t + ii*256; int r = idx >> 6, c = idx & 63;
    tile[r][c] = f2b(in[(size_t)(r0 + r)*C + c0 + c]);
  }
  __syncthreads();
#pragma unroll
  for (int ii = 0; ii < 16; ++ii){
    int idx = t + ii*256; int r = idx >> 6, c = idx & 63;
    outp[(size_t)(c0 + r)*R + r0 + c] = tile[c][r];
  }
}

// ---------------- QKV epilogue for 128-tile fallback path -------------------
__device__ __forceinline__ void qkv_epilogue(
    const f32x4 acc[4][4], const float* bias, int bx, int by,
    int wm, int wn, int lq, int ln,
    u16* qb, u16* kb, u16* vb)
{
  const int tensor = bx >> 4, h = bx & 15, b = by >> 3, t0 = (by & 7)*128;
  u16* tb = tensor==0 ? qb : (tensor==1 ? kb : vb);
  u16* op = tb + ((size_t)(b*NH + h)*T_ + t0)*HD;
#pragma unroll
  for (int j=0;j<4;j++){
    const float bv = bias[bx*128 + wn*64 + j*16 + ln];
    const int n = wn*64 + j*16 + ln;
#pragma unroll
    for (int i=0;i<4;i++){
      const int m0 = wm*64 + i*16 + lq*4;      // C/D: row = quad*4 + reg
#pragma unroll
      for (int r=0;r<4;r++)
        op[(size_t)(m0 + r)*HD + n] = f2b(acc[i][j][r] + bv);
    }
  }
}

// ---------------- QKV GEMM, 256x256 8-phase (R10-proven schedule) -----------
__global__ __launch_bounds__(512,2) void gemm_qkv_8p(
    const u16* __restrict__ Xb, const u16* __restrict__ Wt,
    const float* __restrict__ bias,
    u16* __restrict__ qb, u16* __restrict__ kb, u16* __restrict__ vb)
{
  __shared__ u16 lds[2][2][256*64];            // [buf][A/B][row][k] 128 KiB
  const int t = threadIdx.x;                   // 0..511
  const int lane = t & 63, wid = t >> 6;       // 8 waves: 2M x 4N
  const int lq = lane >> 4, ln = lane & 15;
  const int wm = wid >> 2, wn = wid & 3;

  // XCD-aware swizzle (768 blocks, 768%8==0 -> simple form is bijective)
  const int bid0 = blockIdx.x;
  const int bid = (bid0 & 7)*96 + (bid0 >> 3);
  const int bx = bid % 24, by = bid / 24;      // bx: N/256, by: M/256

  const int rl  = (wid << 4) + (lane >> 3);    // q=0 local row (0..127)
  const int sw0 = (lane & 7) ^ (rl & 7);
  const u16* Ag = Xb + ((size_t)(by*256) + rl)*2048;
  const u16* Bg = Wt + ((size_t)(bx*256) + rl)*2048;
  const size_t q0off = (size_t)sw0*8;
  const size_t q1off = (size_t)8*2048 + (size_t)sw0*8;   // (rl+8)&7 == rl&7

#define STAGE(buf_, op_, h_, T_) do { \
    const u16* s_ = (op_ ? Bg : Ag) + (size_t)(h_)*(128*2048) + (size_t)(T_)*64; \
    const u16* d_ = &lds[buf_][op_][(((h_)*128) + (wid<<4))*64]; \
    glds16(s_ + q0off, d_); \
    glds16(s_ + q1off, d_ + 8*64); \
  } while(0)

  const int swr0 = (0*4 + lq) ^ (ln & 7);
  const int swr1 = (1*4 + lq) ^ (ln & 7);

  const f32x4 fz = {0.f,0.f,0.f,0.f};
  f32x4 acc[8][4];
#pragma unroll
  for (int f=0;f<8;f++)
#pragma unroll
    for (int g=0;g<4;g++) acc[f][g] = fz;

  // prologue: tile0 fully + tile1's Bhi,Blo,Ahi (Alo(1) comes at (0,+0))
  STAGE(0,0,0,0); STAGE(0,0,1,0); STAGE(0,1,0,0); STAGE(0,1,1,0);
  STAGE(1,1,0,1); STAGE(1,1,1,1); STAGE(1,0,0,1);
  asm volatile("s_waitcnt vmcnt(6)" ::: "memory");   // tile0 landed
  sbar();

  for (int T = 0; T < 32; ++T){
    const int b = T & 1;
    const u16* As = lds[b][0];
    const u16* Bs = lds[b][1];
    bf16x8 a0[4][2], a4[4][2], bfr[4][2];

    // ---- phase +0: read A frags 0-3 + all B frags; stage Alo(T+1)
#pragma unroll
    for (int f=0;f<4;f++){
      a0[f][0]  = ldfrag(&As[(wm*128 + f*16 + ln)*64 + swr0*8]);
      a0[f][1]  = ldfrag(&As[(wm*128 + f*16 + ln)*64 + swr1*8]);
      bfr[f][0] = ldfrag(&Bs[(wn*64  + f*16 + ln)*64 + swr0*8]);
      bfr[f][1] = ldfrag(&Bs[(wn*64  + f*16 + ln)*64 + swr1*8]);
    }
    if (T+1 < 32) STAGE(b^1, 0, 1, T+1);
    sbar();
    __builtin_amdgcn_s_setprio(1);
#pragma unroll
    for (int f=0;f<4;f++)
#pragma unroll
      for (int g=0;g<2;g++){
        acc[f][g] = __builtin_amdgcn_mfma_f32_16x16x32_bf16(a0[f][0], bfr[g][0], acc[f][g], 0,0,0);
        acc[f][g] = __builtin_amdgcn_mfma_f32_16x16x32_bf16(a0[f][1], bfr[g][1], acc[f][g], 0,0,0);
      }
    __builtin_amdgcn_s_setprio(0);
    sbar();

    // ---- phase +1: read A frags 4-7; stage Bhi(T+2)
#pragma unroll
    for (int f=0;f<4;f++){
      a4[f][0] = ldfrag(&As[(wm*128 + (f+4)*16 + ln)*64 + swr0*8]);
      a4[f][1] = ldfrag(&As[(wm*128 + (f+4)*16 + ln)*64 + swr1*8]);
    }
    if (T+2 < 32) STAGE(b, 1, 0, T+2);
    sbar();
    __builtin_amdgcn_s_setprio(1);
#pragma unroll
    for (int f=0;f<4;f++)
#pragma unroll
      for (int g=0;g<2;g++){
        acc[f+4][g] = __builtin_amdgcn_mfma_f32_16x16x32_bf16(a4[f][0], bfr[g][0], acc[f+4][g], 0,0,0);
        acc[f+4][g] = __builtin_amdgcn_mfma_f32_16x16x32_bf16(a4[f][1], bfr[g][1], acc[f+4][g], 0,0,0);
      }
    __builtin_amdgcn_s_setprio(0);
    sbar();

    // ---- phase +2: no reads; stage Blo(T+2)
    if (T+2 < 32) STAGE(b, 1, 1, T+2);
    sbar();
    __builtin_amdgcn_s_setprio(1);
#pragma unroll
    for (int f=0;f<4;f++)
#pragma unroll
      for (int g=2;g<4;g++){
        acc[f+4][g] = __builtin_amdgcn_mfma_f32_16x16x32_bf16(a4[f][0], bfr[g][0], acc[f+4][g], 0,0,0);
        acc[f+4][g] = __builtin_amdgcn_mfma_f32_16x16x32_bf16(a4[f][1], bfr[g][1], acc[f+4][g], 0,0,0);
      }
    __builtin_amdgcn_s_setprio(0);
    sbar();

    // ---- phase +3: no reads; stage Ahi(T+2); counted vmcnt
    if (T+2 < 32) STAGE(b, 0, 0, T+2);
    if (T >= 30) asm volatile("s_waitcnt vmcnt(0)" ::: "memory");
    else         asm volatile("s_waitcnt vmcnt(6)" ::: "memory");
    sbar();
    __builtin_amdgcn_s_setprio(1);
#pragma unroll
    for (int f=0;f<4;f++)
#pragma unroll
      for (int g=2;g<4;g++){
        acc[f][g] = __builtin_amdgcn_mfma_f32_16x16x32_bf16(a0[f][0], bfr[g][0], acc[f][g], 0,0,0);
        acc[f][g] = __builtin_amdgcn_mfma_f32_16x16x32_bf16(a0[f][1], bfr[g][1], acc[f][g], 0,0,0);
      }
    __builtin_amdgcn_s_setprio(0);
    sbar();
  }
#undef STAGE

  // epilogue: scatter to Q/K/V [BH][T][HD]
  const int tensor = bx >> 3;
  u16* tb = tensor==0 ? qb : (tensor==1 ? kb : vb);
  const int m_base = by*256 + wm*128;
#pragma unroll
  for (int g=0; g<4; ++g){
    const int ncol = (bx & 7)*256 + wn*64 + g*16 + ln;   // 0..2047 in tensor
    const float bv = bias[tensor*2048 + ncol];
    const int h = ncol >> 7, d = ncol & 127;
#pragma unroll
    for (int f=0; f<8; ++f){
      const int m0 = m_base + f*16 + lq*4;
      const int bb = m0 >> 10, tt = m0 & 1023;           // rows m0..m0+3 same b
      u16* op = tb + ((size_t)(bb*NH + h)*T_ + tt)*HD + d;
#pragma unroll
      for (int r=0;r<4;++r)
        op[(size_t)r*HD] = f2b(acc[f][g][r] + bv);
    }
  }
}

// ---------------- proj GEMM, 256x256 8-phase (R10-proven schedule) ----------
__global__ __launch_bounds__(512,2) void gemm_proj_8p(
    const u16* __restrict__ Y, const u16* __restrict__ Wt,
    const float* __restrict__ bias, float* __restrict__ outp)
{
  __shared__ u16 lds[2][2][256*64];            // [buf][A/B][row][k] 128 KiB
  const int t = threadIdx.x;
  const int lane = t & 63, wid = t >> 6;
  const int lq = lane >> 4, ln = lane & 15;
  const int wm = wid >> 2, wn = wid & 3;

  // 256 blocks, 256%8==0 -> bijective XCD swizzle
  const int bid0 = blockIdx.x;
  const int bid = (bid0 & 7)*32 + (bid0 >> 3);
  const int bx = bid & 7, by = bid >> 3;       // bx: N/256 (8), by: M/256 (32)

  const int rl  = (wid << 4) + (lane >> 3);
  const int sw0 = (lane & 7) ^ (rl & 7);
  const u16* Bg = Wt + ((size_t)(bx*256) + rl)*2048;
  const size_t bq0 = (size_t)sw0*8;
  const size_t arow0 = ((size_t)(by >> 2)*16)*1024 + (size_t)(by & 3)*256 + rl;

#define STAGEP(buf_, op_, h_, Tt_) do { \
    const u16* d_ = &lds[buf_][op_][(((h_)*128) + (wid<<4))*64]; \
    if (op_){ \
      const u16* s_ = Bg + (size_t)(h_)*(128*2048) + (size_t)(Tt_)*64; \
      glds16(s_ + bq0, d_); \
      glds16(s_ + (size_t)8*2048 + bq0, d_ + 8*64); \
    } else { \
      const u16* s_ = Y + (arow0 + (size_t)((Tt_) >> 1)*1024 + (size_t)(h_)*128)*128 \
                        + ((Tt_) & 1)*64 + sw0*8; \
      glds16(s_, d_); \
      glds16(s_ + 8*128, d_ + 8*64); \
    } \
  } while(0)

  const int swr0 = (0*4 + lq) ^ (ln & 7);
  const int swr1 = (1*4 + lq) ^ (ln & 7);

  const f32x4 fz = {0.f,0.f,0.f,0.f};
  f32x4 acc[8][4];
#pragma unroll
  for (int f=0;f<8;f++)
#pragma unroll
    for (int g=0;g<4;g++) acc[f][g] = fz;

  STAGEP(0,0,0,0); STAGEP(0,0,1,0); STAGEP(0,1,0,0); STAGEP(0,1,1,0);
  STAGEP(1,1,0,1); STAGEP(1,1,1,1); STAGEP(1,0,0,1);
  asm volatile("s_waitcnt vmcnt(6)" ::: "memory");
  sbar();

  for (int T = 0; T < 32; ++T){
    const int b = T & 1;
    const u16* As = lds[b][0];
    const u16* Bs = lds[b][1];
    bf16x8 a0[4][2], a4[4][2], bfr[4][2];

#pragma unroll
    for (int f=0;f<4;f++){
      a0[f][0]  = ldfrag(&As[(wm*128 + f*16 + ln)*64 + swr0*8]);
      a0[f][1]  = ldfrag(&As[(wm*128 + f*16 + ln)*64 + swr1*8]);
      bfr[f][0] = ldfrag(&Bs[(wn*64  + f*16 + ln)*64 + swr0*8]);
      bfr[f][1] = ldfrag(&Bs[(wn*64  + f*16 + ln)*64 + swr1*8]);
    }
    if (T+1 < 32) STAGEP(b^1, 0, 1, T+1);
    sbar();
    __builtin_amdgcn_s_setprio(1);
#pragma unroll
    for (int f=0;f<4;f++)
#pragma unroll
      for (int g=0;g<2;g++){
        acc[f][g] = __builtin_amdgcn_mfma_f32_16x16x32_bf16(a0[f][0], bfr[g][0], acc[f][g], 0,0,0);
        acc[f][g] = __builtin_amdgcn_mfma_f32_16x16x32_bf16(a0[f][1], bfr[g][1], acc[f][g], 0,0,0);
      }
    __builtin_amdgcn_s_setprio(0);
    sbar();

#pragma unroll
    for (int f=0;f<4;f++){
      a4[f][0] = ldfrag(&As[(wm*128 + (f+4)*16 + ln)*64 + swr0*8]);
      a4[f][1] = ldfrag(&As[(wm*128 + (f+4)*16 + ln)*64 + swr1*8]);
    }
    if (T+2 < 32) STAGEP(b, 1, 0, T+2);
    sbar();
    __builtin_amdgcn_s_setprio(1);
#pragma unroll
    for (int f=0;f<4;f++)
#pragma unroll
      for (int g=0;g<2;g++){
        acc[f+4][g] = __builtin_amdgcn_mfma_f32_16x16x32_bf16(a4[f][0], bfr[g][0], acc[f+4][g], 0,0,0);
        acc[f+4][g] = __builtin_amdgcn_mfma_f32_16x16x32_bf16(a4[f][1], bfr[g][1], acc[f+4][g], 0,0,0);
      }
    __builtin_amdgcn_s_setprio(0);
    sbar();

    if (T+2 < 32) STAGEP(b, 1, 1, T+2);
    sbar();
    __builtin_amdgcn_s_setprio(1);
#pragma unroll
    for (int f=0;f<4;f++)
#pragma unroll
      for (int g=2;g<4;g++){
        acc[f+4][g] = __builtin_amdgcn_mfma_f32_16x16x32_bf16(a4[f][0], bfr[g][0], acc[f+4][g], 0,0,0);
        acc[f+4][g] = __builtin_amdgcn_mfma_f32_16x16x32_bf16(a4[f][1], bfr[g][1], acc[f+4][g], 0,0,0);
      }
    __builtin_amdgcn_s_setprio(0);
    sbar();

    if (T+2 < 32) STAGEP(b, 0, 0, T+2);
    if (T >= 30) asm volatile("s_waitcnt vmcnt(0)" ::: "memory");
    else         asm volatile("s_waitcnt vmcnt(6)" ::: "memory");
    sbar();
    __builtin_amdgcn_s_setprio(1);
#pragma unroll
    for (int f=0;f<4;f++)
#pragma unroll
      for (int g=2;g<4;g++){
        acc[f][g] = __builtin_amdgcn_mfma_f32_16x16x32_bf16(a0[f][0], bfr[g][0], acc[f][g], 0,0,0);
        acc[f][g] = __builtin_amdgcn_mfma_f32_16x16x32_bf16(a0[f][1], bfr[g][1], acc[f][g], 0,0,0);
      }
    __builtin_amdgcn_s_setprio(0);
    sbar();
  }
#undef STAGEP

  // epilogue: fp32 out [8192][2048]
  const int m_base = by*256 + wm*128;
#pragma unroll
  for (int g=0; g<4; ++g){
    const int ncol = bx*256 + wn*64 + g*16 + ln;
    const float bv = bias[ncol];
#pragma unroll
    for (int f=0; f<8; ++f){
      const int m0 = m_base + f*16 + lq*4;
      float* op = outp + (size_t)m0*2048 + ncol;
#pragma unroll
      for (int r=0;r<4;++r)
        op[(size_t)r*2048] = acc[f][g][r] + bv;
    }
  }
}

// ---------------- QKV GEMM, fallback: A = x fp32 (cvt in staging). ----------
__global__ __launch_bounds__(256,2) void gemm_qkv_f32(
    const float* __restrict__ X, const u16* __restrict__ Wt, const float* __restrict__ bias,
    u16* __restrict__ qb, u16* __restrict__ kb, u16* __restrict__ vb)
{
  __shared__ u16 As[128*32];
  __shared__ u16 Bs[128*32];
  const int t = threadIdx.x;
  const int bx = blockIdx.x, by = blockIdx.y;
  const int lane = t & 63, wv = t >> 6;
  const int lq = lane >> 4, ln = lane & 15;
  const int wm = wv >> 1, wn = wv & 1;

  const int ar = t >> 1, ah = t & 1;
  const float* Ap = X + (size_t)(by*128 + ar)*2048 + ah*16;
  u16* AsW = &As[ar*32 + ah*16];

  const int c0 = t, c1 = 256 + t;
  const u16* Bp0 = Wt + (size_t)(bx*128 + (c0 >> 2))*2048 + (c0 & 3)*8;
  const u16* Bp1 = Wt + (size_t)(bx*128 + (c1 >> 2))*2048 + (c1 & 3)*8;
  const u16* BsW0 = &Bs[(wv*64)*8];
  const u16* BsW1 = &Bs[(256 + wv*64)*8];

  const f32x4 fz = {0.f,0.f,0.f,0.f};
  f32x4 acc[4][4];
#pragma unroll
  for (int i=0;i<4;i++)
#pragma unroll
    for (int j=0;j<4;j++) acc[i][j] = fz;

  for (int kt = 0; kt < 64; ++kt){
    float4 a0 = *(const float4*)(Ap);
    float4 a1 = *(const float4*)(Ap + 4);
    float4 a2 = *(const float4*)(Ap + 8);
    float4 a3 = *(const float4*)(Ap + 12);
    Ap += 32;
    __syncthreads();
    uint4 w0, w1;
    w0.x = pk2(a0.x,a0.y); w0.y = pk2(a0.z,a0.w);
    w0.z = pk2(a1.x,a1.y); w0.w = pk2(a1.z,a1.w);
    w1.x = pk2(a2.x,a2.y); w1.y = pk2(a2.z,a2.w);
    w1.z = pk2(a3.x,a3.y); w1.w = pk2(a3.z,a3.w);
    *(uint4*)(AsW) = w0; *(uint4*)(AsW + 8) = w1;
    glds16(Bp0, BsW0);
    glds16(Bp1, BsW1);
    Bp0 += 32; Bp1 += 32;
    __syncthreads();
    bf16x8 af[4], bf[4];
#pragma unroll
    for (int i=0;i<4;i++) af[i] = ldfrag(&As[(wm*64 + i*16 + ln)*32 + lq*8]);
#pragma unroll
    for (int j=0;j<4;j++) bf[j] = ldfrag(&Bs[(wn*64 + j*16 + ln)*32 + lq*8]);
#pragma unroll
    for (int i=0;i<4;i++)
#pragma unroll
      for (int j=0;j<4;j++)
        acc[i][j] = __builtin_amdgcn_mfma_f32_16x16x32_bf16(af[i], bf[j], acc[i][j], 0,0,0);
  }
  qkv_epilogue(acc, bias, bx, by, wm, wn, lq, ln, qb, kb, vb);
}

// ---------------- flash attention, R14: XCD-local grid + packed V-stage -----
// grid (BH, 8): id%8 = bh%8 -> all 8 q-blocks of one bh share an XCD; K/V
// (512KB/bh, ~8 resident bh = 4MB) become L2-resident. qt = 7-blockIdx.y
// keeps heavy-first. V-stage: thread owns keys (2p,2p+1), d dh*16..+15;
// writes 16x ds_write_b32 (slot = 2p^((d&7)<<3); pair stays adjacent).
__global__ __launch_bounds__(256,2) void attn_fwd(
    u16* qy, const u16* __restrict__ kk, const u16* __restrict__ vv)
{
  __shared__ u16 Ks[2][64*128];                // [buf][key][d], swizzled
  __shared__ u16 Vt[2][128*64];                // [buf][d][key], swizzled
  const int bh = blockIdx.x, qt = 7 - blockIdx.y;
  const int t = threadIdx.x;
  const int lane = t & 63, wv = t >> 6;
  const int lq = lane >> 4, ln = lane & 15;

  bf16x8 qf[2][4];                             // per-lane: Q[i*16+ln][kc*32+lq*8..]
#pragma unroll
  for (int i=0;i<2;i++)
#pragma unroll
    for (int kc=0;kc<4;kc++){
      int qrow = qt*128 + wv*32 + i*16 + ln;
      qf[i][kc] = ldfrag(&qy[((size_t)bh*T_ + qrow)*HD + kc*32 + lq*8]);
    }

  const f32x4 fz = {0.f,0.f,0.f,0.f};
  f32x4 o[2][8];                               // O^T frags
#pragma unroll
  for (int i=0;i<2;i++)
#pragma unroll
    for (int jd=0;jd<8;jd++) o[i][jd] = fz;
  float mi[2] = {-1e30f, -1e30f}, li[2] = {0.f, 0.f};

  const float scale = 0.08838834764831843f;    // 1/sqrt(128)
  const int vp = t & 31, vdh = t >> 5;         // V-stage: key pair 2vp, d vdh*16..
  const int nkt = 2*qt + 2;                    // causal: keys < (qt+1)*128

  uint4 kreg[4];
  uint4 vr[4];                                 // [row0 d0-7, row0 d8-15, row1 ..]
  {
    const uint4* ksrc = (const uint4*)(kk + (size_t)bh*T_*HD);
#pragma unroll
    for (int ii=0; ii<4; ++ii) kreg[ii] = ksrc[t + ii*256];
    const u16* v0 = &vv[((size_t)bh*T_ + 2*vp)*HD + vdh*16];
    vr[0] = *(const uint4*)(v0);
    vr[1] = *(const uint4*)(v0 + 8);
    vr[2] = *(const uint4*)(v0 + HD);
    vr[3] = *(const uint4*)(v0 + HD + 8);
  }

  for (int kt = 0; kt < nkt; ++kt){
    const int b = kt & 1;
    uint4* kdst = (uint4*)Ks[b];
#pragma unroll
    for (int ii=0; ii<4; ++ii){
      const int c = t + ii*256;                // chunk: row c>>4, slot c&15
      kdst[(c & ~15) | ((c & 15) ^ ((c >> 4) & 7))] = kreg[ii];
    }
    // packed V transpose: u32 = (V[2vp][d], V[2vp+1][d]) -> Vt[d][2vp^sw..+1]
#pragma unroll
    for (int half=0; half<2; ++half){
      const u16* e0 = (const u16*)&vr[half];
      const u16* e1 = (const u16*)&vr[2+half];
#pragma unroll
      for (int j=0; j<8; ++j){
        const int d = vdh*16 + half*8 + j;     // d&7 == j
        const u32 w = (u32)e0[j] | ((u32)e1[j] << 16);
        *(u32*)&Vt[b][d*64 + ((2*vp) ^ (j<<3))] = w;
      }
    }
    {
      const int ktn = (kt+1 < nkt) ? kt+1 : kt;   // last iter: harmless reload
      const uint4* ksrc = (const uint4*)(kk + ((size_t)bh*T_ + ktn*64)*HD);
#pragma unroll
      for (int ii=0; ii<4; ++ii) kreg[ii] = ksrc[t + ii*256];
      const u16* v0 = &vv[((size_t)bh*T_ + ktn*64 + 2*vp)*HD + vdh*16];
      vr[0] = *(const uint4*)(v0);
      vr[1] = *(const uint4*)(v0 + 8);
      vr[2] = *(const uint4*)(v0 + HD);
      vr[3] = *(const uint4*)(v0 + HD + 8);
    }
    __syncthreads();                           // buffer b fully written

    const bool active = (kt*64) <= (qt*128 + wv*32 + 31);
    if (active){

    // S^T = K Q^T (operand-swapped: A=K frag, B=Q frag; same reg layouts)
    f32x4 s[2][4];
#pragma unroll
    for (int i=0;i<2;i++)
#pragma unroll
      for (int j=0;j<4;j++) s[i][j] = fz;
    __builtin_amdgcn_s_setprio(1);
#pragma unroll
    for (int j=0;j<4;j++){
      bf16x8 kf[4];
      const int krow = j*16 + ln;
      const int ksw = (krow & 7) << 3;
#pragma unroll
      for (int kc=0;kc<4;kc++)
        kf[kc] = ldfrag(&Ks[b][krow*128 + ((kc*32 + lq*8) ^ ksw)]);
#pragma unroll
      for (int i=0;i<2;i++)
#pragma unroll
        for (int kc=0;kc<4;kc++)
          s[i][j] = __builtin_amdgcn_mfma_f32_16x16x32_bf16(kf[kc], qf[i][kc], s[i][j], 0,0,0);
    }
    __builtin_amdgcn_s_setprio(0);

    // scale + causal mask: q = ..+i*16+ln (col), key = kt*64+j*16+lq*4+r (row)
#pragma unroll
    for (int i=0;i<2;i++){
      const int qg = qt*128 + wv*32 + i*16 + ln;
#pragma unroll
      for (int j=0;j<4;j++)
#pragma unroll
        for (int r=0;r<4;r++){
          const int kg = kt*64 + j*16 + lq*4 + r;
          float sv = s[i][j][r]*scale;
          s[i][j][r] = (kg > qg) ? -1e30f : sv;
        }
    }

    // in-register softmax per q-row (16 vals/lane + 2 shuffles), defer-max THR=8
    float mx[2];
#pragma unroll
    for (int i=0;i<2;i++){
      float m = s[i][0][0];
#pragma unroll
      for (int j=0;j<4;j++)
#pragma unroll
        for (int r=0;r<4;r++) m = fmaxf(m, s[i][j][r]);
      m = fmaxf(m, __shfl_xor(m, 16));
      m = fmaxf(m, __shfl_xor(m, 32));
      mx[i] = m;
    }
    bool ok = (mx[0] <= mi[0] + 8.0f) && (mx[1] <= mi[1] + 8.0f);
    if (!__all((int)ok)){
#pragma unroll
      for (int i=0;i<2;i++){
        float mnew = fmaxf(mi[i], mx[i]);
        float alpha = __expf(mi[i] - mnew);
        li[i] *= alpha;
        mi[i] = mnew;
#pragma unroll
        for (int jd=0;jd<8;jd++)
#pragma unroll
          for (int r=0;r<4;r++) o[i][jd][r] *= alpha;
      }
    }
#pragma unroll
    for (int i=0;i<2;i++){
      float rs = 0.f;
#pragma unroll
      for (int j=0;j<4;j++)
#pragma unroll
        for (int r=0;r<4;r++){
          float p = __expf(s[i][j][r] - mi[i]);   // bounded by e^8
          s[i][j][r] = p; rs += p;
        }
      rs += __shfl_xor(rs, 16);
      rs += __shfl_xor(rs, 32);
      li[i] += rs;
    }

    // PV: O^T += V^T P^T under k-permutation pi(lq,e).
    bf16x8 pb[2][2];
#pragma unroll
    for (int i=0;i<2;i++)
#pragma unroll
      for (int c=0;c<2;c++){
        uint4 w;
        w.x = pk2(s[i][c][0],   s[i][c][1]);
        w.y = pk2(s[i][c][2],   s[i][c][3]);
        w.z = pk2(s[i][c+2][0], s[i][c+2][1]);
        w.w = pk2(s[i][c+2][2], s[i][c+2][3]);
        pb[i][c] = __builtin_bit_cast(bf16x8, w);
      }
    __builtin_amdgcn_s_setprio(1);
#pragma unroll
    for (int jd=0;jd<8;jd++){
      const int vrow = jd*16 + ln;
      const int vsw = (vrow & 7) << 3;
#pragma unroll
      for (int c=0;c<2;c++){
        uint2 vlo = *(const uint2*)&Vt[b][vrow*64 + ((c*16     + lq*4) ^ vsw)];
        uint2 vhi = *(const uint2*)&Vt[b][vrow*64 + (((c+2)*16 + lq*4) ^ vsw)];
        uint4 vw; vw.x = vlo.x; vw.y = vlo.y; vw.z = vhi.x; vw.w = vhi.y;
        const bf16x8 va = __builtin_bit_cast(bf16x8, vw);
#pragma unroll
        for (int i=0;i<2;i++)
          o[i][jd] = __builtin_amdgcn_mfma_f32_16x16x32_bf16(va, pb[i][c], o[i][jd], 0,0,0);
      }
    }
    __builtin_amdgcn_s_setprio(0);

    } // active
  }

  // epilogue: packed 8B stores; lane holds q=..+i*16+ln, d=jd*16+lq*4+r
#pragma unroll
  for (int i=0;i<2;i++){
    const float inv = 1.f / li[i];
    const int q = qt*128 + wv*32 + i*16 + ln;
#pragma unroll
    for (int jd=0;jd<8;jd++){
      ushort4 w;
      w.x = f2b(o[i][jd][0] * inv);
      w.y = f2b(o[i][jd][1] * inv);
      w.z = f2b(o[i][jd][2] * inv);
      w.w = f2b(o[i][jd][3] * inv);
      *(ushort4*)&qy[((size_t)bh*T_ + q)*HD + jd*16 + lq*4] = w;
    }
  }
}

extern "C" void kernel_launch(void* const* d_in, const int* in_sizes, int n_in,
                              void* d_out, int out_size, void* d_ws, size_t ws_size,
                              hipStream_t stream)
{
  const float* x      = (const float*)d_in[0];   // [8192][2048] fp32
  const float* W_attn = (const float*)d_in[1];   // [2048][6144] fp32
  const float* b_attn = (const float*)d_in[2];   // [6144] fp32
  const float* W_proj = (const float*)d_in[3];   // [2048][2048] fp32
  const float* b_proj = (const float*)d_in[4];   // [2048] fp32
  float* out = (float*)d_out;                    // [8192][2048] fp32

  u16* Wat = (u16*)d_ws;                         // [6144][2048] bf16 = W_attn^T
  u16* Wpt = Wat + (size_t)6144*2048;            // [2048][2048] bf16 = W_proj^T
  u16* qb  = Wpt + (size_t)2048*2048;            // Q bf16, then y bf16
  u16* xb  = qb  + (size_t)BH*T_*HD;             // x bf16 (only if ws >= 96 MiB)
  u16* kb  = (u16*)d_out;                        // K bf16 (d_out low half)
  u16* vb  = kb + (size_t)BH*T_*HD;              // V bf16 (d_out high half)

  const size_t need = ((size_t)6144*2048 + (size_t)2048*2048
                       + 2*(size_t)BH*T_*HD) * sizeof(u16);   // 96 MiB
  const int big_ws = (ws_size >= need) ? 1 : 0;

  hipLaunchKernelGGL(prep, dim3(96,32,2), dim3(256,1,1), 0, stream,
                     W_attn, Wat, W_proj, Wpt,
                     (const float4*)x, (ushort4*)xb, big_ws);
  if (big_ws){
    hipLaunchKernelGGL(gemm_qkv_8p, dim3(768,1,1), dim3(512,1,1), 0, stream,
                       xb, Wat, b_attn, qb, kb, vb);
  } else {
    hipLaunchKernelGGL(gemm_qkv_f32, dim3(48,64,1), dim3(256,1,1), 0, stream,
                       x, Wat, b_attn, qb, kb, vb);
  }
  hipLaunchKernelGGL(attn_fwd, dim3(BH,8,1), dim3(256,1,1), 0, stream,
                     qb, kb, vb);
  hipLaunchKernelGGL(gemm_proj_8p, dim3(256,1,1), dim3(512,1,1), 0, stream,
                     qb, Wpt, b_proj, out);
}